// Round 5
// baseline (259.249 us; speedup 1.0000x reference)
//
#include <hip/hip_runtime.h>

typedef unsigned short u16;
typedef __bf16 bf16x8 __attribute__((ext_vector_type(8)));
typedef float f32x4 __attribute__((ext_vector_type(4)));

__device__ __forceinline__ u16 f2bf(float f) {
  unsigned int u = __builtin_bit_cast(unsigned int, f);
  u += 0x7fffu + ((u >> 16) & 1u);
  return (u16)(u >> 16);
}
__device__ __forceinline__ float bf2f(u16 h) {
  unsigned int u = ((unsigned int)h) << 16;
  return __builtin_bit_cast(float, u);
}

// ---------------------------------------------------------------------------
// k_prep: fp32 weights -> bf16 MFMA B-fragment order.
// Fragment (ks, nt, lane): 8 elems W[ks*32 + (lane>>4)*8 + j][nt*16 + (lane&15)]
// at dst[((ks*16+nt)*64 + lane)*8 + j].
// ---------------------------------------------------------------------------
__global__ __launch_bounds__(256) void k_prep(
    const float* __restrict__ W1, const float* __restrict__ W2,
    const float* __restrict__ R1, const float* __restrict__ R2, const float* __restrict__ R3,
    u16* __restrict__ W1s, u16* __restrict__ W2s,
    u16* __restrict__ R1s, u16* __restrict__ R2s, u16* __restrict__ R3s) {
  int t = blockIdx.x * 256 + threadIdx.x;
  const float* src; u16* dst; int lt;
  if (t < 12288) { src = W1; dst = W1s; lt = t; }
  else {
    int u = t - 12288;
    int m = u >> 13;
    lt = u & 8191;
    if (m == 0)      { src = W2; dst = W2s; }
    else if (m == 1) { src = R1; dst = R1s; }
    else if (m == 2) { src = R2; dst = R2s; }
    else if (m == 3) { src = R3; dst = R3s; }
    else return;
  }
  int lane = lt & 63;
  int nt = (lt >> 6) & 15;
  int ks = lt >> 10;
  int col = nt * 16 + (lane & 15);
  int kb = ks * 32 + (lane >> 4) * 8;
  union { u16 u[8]; uint4 v; } o;
#pragma unroll
  for (int j = 0; j < 8; ++j) o.u[j] = f2bf(src[(size_t)(kb + j) * 256 + col]);
  *(uint4*)(dst + (size_t)lt * 8) = o.v;
}

// ---------------------------------------------------------------------------
// CSR build: histogram -> 3-stage multi-block exclusive scan -> scatter.
// ---------------------------------------------------------------------------
__global__ __launch_bounds__(256) void k_hist(const int* __restrict__ cells,
                                              int* __restrict__ counts, int E) {
  int e = blockIdx.x * 256 + threadIdx.x;
  if (e < E) atomicAdd(&counts[cells[e]], 1);
}

__global__ __launch_bounds__(256) void k_scan1(const int* __restrict__ counts,
                                               int* __restrict__ offs,
                                               int* __restrict__ bsum, int M) {
  __shared__ int ws[4];
  int tid = threadIdx.x, lane = tid & 63, wid = tid >> 6;
  int i = blockIdx.x * 256 + tid;
  int v = (i < M) ? counts[i] : 0;
  int x = v;
#pragma unroll
  for (int s = 1; s < 64; s <<= 1) { int y = __shfl_up(x, s); if (lane >= s) x += y; }
  if (lane == 63) ws[wid] = x;
  __syncthreads();
  int pre = 0;
#pragma unroll
  for (int w = 0; w < 4; ++w) if (w < wid) pre += ws[w];
  if (i < M) offs[i] = pre + x - v;
  if (tid == 255) bsum[blockIdx.x] = pre + x;
}

__global__ __launch_bounds__(256) void k_scan2(int* __restrict__ bsum, int nb) {
  __shared__ int ws[4];
  int tid = threadIdx.x, lane = tid & 63, wid = tid >> 6;
  int v = (tid < nb) ? bsum[tid] : 0;
  int x = v;
#pragma unroll
  for (int s = 1; s < 64; s <<= 1) { int y = __shfl_up(x, s); if (lane >= s) x += y; }
  if (lane == 63) ws[wid] = x;
  __syncthreads();
  int pre = 0;
#pragma unroll
  for (int w = 0; w < 4; ++w) if (w < wid) pre += ws[w];
  if (tid < nb) bsum[tid] = pre + x - v;
}

__global__ __launch_bounds__(256) void k_scan3(int* __restrict__ offs,
                                               const int* __restrict__ bsum,
                                               int* __restrict__ cursor, int M, int E) {
  int i = blockIdx.x * 256 + threadIdx.x;
  if (i < M) { int o = offs[i] + bsum[blockIdx.x]; offs[i] = o; cursor[i] = o; }
  if (i == M) offs[M] = E;
}

__global__ __launch_bounds__(256) void k_scatter(const int* __restrict__ cells,
                                                 const int* __restrict__ nodes,
                                                 int* __restrict__ cursor,
                                                 int* __restrict__ sorted, int E) {
  int e = blockIdx.x * 256 + threadIdx.x;
  if (e < E) {
    int c = cells[e];
    int p = atomicAdd(&cursor[c], 1);
    sorted[p] = nodes[e];
  }
}

// ---------------------------------------------------------------------------
// k_phi: H = relu(relu(X@W1+b1)@W2+b2). 128 rows/block (8 m-tiles/wave),
// wave w owns cols [w*64, w*64+64). Single 64KB LDS buffer time-shared by
// X-tile / h1 / h2 (XOR swizzle ^((row&15)<<3) in u16 units, 0 conflicts).
// X loaded NON-TEMPORAL (read-once; keeps weight tables L2/L3-resident).
// 2 blocks/CU (LDS-capped). Weight fetch per block amortized over 2x MFMA.
// ---------------------------------------------------------------------------
__global__ __launch_bounds__(256) void k_phi(
    const float* __restrict__ X,
    const u16* __restrict__ W1s, const float* __restrict__ b1,
    const u16* __restrict__ W2s, const float* __restrict__ b2,
    u16* __restrict__ H, int N) {
  __shared__ __align__(16) u16 buf[128 * 256];
  const int tid = threadIdx.x, lane = tid & 63, wid = tid >> 6;
  const int g = lane >> 4, r16 = lane & 15;
  const int rbase = blockIdx.x * 128;

  const u16* w1p = W1s + (size_t)(wid * 4) * 512 + lane * 8;  // + ks*8192 + n*512
  const u16* w2p = W2s + (size_t)(wid * 4) * 512 + lane * 8;

  // ---- stage phase 0: X cols [0,256) ----
#pragma unroll 8
  for (int it = 0; it < 32; ++it) {
    int u = it * 256 + tid;
    int row = u >> 6, c4 = u & 63;
    int crow = rbase + row; crow = crow < N ? crow : N - 1;
    f32x4 v = __builtin_nontemporal_load((const f32x4*)(X + (size_t)crow * 384 + c4 * 4));
    uint2 pk;
    pk.x = (unsigned int)f2bf(v[0]) | ((unsigned int)f2bf(v[1]) << 16);
    pk.y = (unsigned int)f2bf(v[2]) | ((unsigned int)f2bf(v[3]) << 16);
    *(uint2*)(buf + row * 256 + ((c4 * 4) ^ ((row & 15) << 3))) = pk;
  }
  __syncthreads();

  f32x4 acc[8][4];
#pragma unroll
  for (int m = 0; m < 8; ++m)
#pragma unroll
    for (int n = 0; n < 4; ++n) acc[m][n] = (f32x4){0.f, 0.f, 0.f, 0.f};

  // ---- layer 1, K phase 0 (ks 0..7) ----
#pragma unroll
  for (int ks = 0; ks < 8; ++ks) {
    bf16x8 bfr[4];
#pragma unroll
    for (int n = 0; n < 4; ++n)
      bfr[n] = *(const bf16x8*)(w1p + (size_t)ks * 8192 + n * 512);
#pragma unroll
    for (int m = 0; m < 8; ++m) {
      int row = m * 16 + r16;
      bf16x8 af = *(const bf16x8*)(buf + row * 256 + ((ks * 32 + g * 8) ^ (r16 << 3)));
#pragma unroll
      for (int n = 0; n < 4; ++n)
        acc[m][n] = __builtin_amdgcn_mfma_f32_16x16x32_bf16(af, bfr[n], acc[m][n], 0, 0, 0);
    }
  }
  __syncthreads();  // done reading phase-0 A

  // ---- stage phase 1: X cols [256,384) into buf u16-cols [0,128) ----
#pragma unroll 8
  for (int it = 0; it < 16; ++it) {
    int u = it * 256 + tid;
    int row = u >> 5, c4 = u & 31;
    int crow = rbase + row; crow = crow < N ? crow : N - 1;
    f32x4 v = __builtin_nontemporal_load((const f32x4*)(X + (size_t)crow * 384 + 256 + c4 * 4));
    uint2 pk;
    pk.x = (unsigned int)f2bf(v[0]) | ((unsigned int)f2bf(v[1]) << 16);
    pk.y = (unsigned int)f2bf(v[2]) | ((unsigned int)f2bf(v[3]) << 16);
    *(uint2*)(buf + row * 256 + ((c4 * 4) ^ ((row & 15) << 3))) = pk;
  }
  __syncthreads();

  // ---- layer 1, K phase 1 (ks 8..11) ----
#pragma unroll
  for (int ksl = 0; ksl < 4; ++ksl) {
    bf16x8 bfr[4];
#pragma unroll
    for (int n = 0; n < 4; ++n)
      bfr[n] = *(const bf16x8*)(w1p + (size_t)(8 + ksl) * 8192 + n * 512);
#pragma unroll
    for (int m = 0; m < 8; ++m) {
      int row = m * 16 + r16;
      bf16x8 af = *(const bf16x8*)(buf + row * 256 + ((ksl * 32 + g * 8) ^ (r16 << 3)));
#pragma unroll
      for (int n = 0; n < 4; ++n)
        acc[m][n] = __builtin_amdgcn_mfma_f32_16x16x32_bf16(af, bfr[n], acc[m][n], 0, 0, 0);
    }
  }
  __syncthreads();  // done reading phase-1 A; buf free for h1

  // ---- h1 = relu(acc + b1) -> buf ----
  float bias1[4];
#pragma unroll
  for (int n = 0; n < 4; ++n) bias1[n] = b1[wid * 64 + n * 16 + r16];
#pragma unroll
  for (int m = 0; m < 8; ++m)
#pragma unroll
    for (int n = 0; n < 4; ++n)
#pragma unroll
      for (int rr = 0; rr < 4; ++rr) {
        int row = m * 16 + g * 4 + rr;
        int col = wid * 64 + n * 16 + r16;
        float v = fmaxf(acc[m][n][rr] + bias1[n], 0.f);
        buf[row * 256 + (col ^ ((row & 15) << 3))] = f2bf(v);
      }
  __syncthreads();

  // ---- layer 2 (reuse acc) ----
#pragma unroll
  for (int m = 0; m < 8; ++m)
#pragma unroll
    for (int n = 0; n < 4; ++n) acc[m][n] = (f32x4){0.f, 0.f, 0.f, 0.f};
#pragma unroll
  for (int ks = 0; ks < 8; ++ks) {
    bf16x8 bfr[4];
#pragma unroll
    for (int n = 0; n < 4; ++n)
      bfr[n] = *(const bf16x8*)(w2p + (size_t)ks * 8192 + n * 512);
#pragma unroll
    for (int m = 0; m < 8; ++m) {
      int row = m * 16 + r16;
      bf16x8 af = *(const bf16x8*)(buf + row * 256 + ((ks * 32 + g * 8) ^ (r16 << 3)));
#pragma unroll
      for (int n = 0; n < 4; ++n)
        acc[m][n] = __builtin_amdgcn_mfma_f32_16x16x32_bf16(af, bfr[n], acc[m][n], 0, 0, 0);
    }
  }
  __syncthreads();  // done reading h1

  // ---- h2 = relu(acc + b2) -> buf ----
  float bias2[4];
#pragma unroll
  for (int n = 0; n < 4; ++n) bias2[n] = b2[wid * 64 + n * 16 + r16];
#pragma unroll
  for (int m = 0; m < 8; ++m)
#pragma unroll
    for (int n = 0; n < 4; ++n)
#pragma unroll
      for (int rr = 0; rr < 4; ++rr) {
        int row = m * 16 + g * 4 + rr;
        int col = wid * 64 + n * 16 + r16;
        float v = fmaxf(acc[m][n][rr] + bias2[n], 0.f);
        buf[row * 256 + (col ^ ((row & 15) << 3))] = f2bf(v);
      }
  __syncthreads();

  // ---- coalesced copy out (normal stores: H is re-read by k_cellsum) ----
#pragma unroll 8
  for (int it = 0; it < 16; ++it) {
    int u = it * 256 + tid;
    int row = u >> 5, k8 = u & 31;
    uint4 d = *(const uint4*)(buf + row * 256 + ((k8 * 8) ^ ((row & 15) << 3)));
    int grow = rbase + row;
    if (grow < N) *(uint4*)(H + (size_t)grow * 256 + k8 * 8) = d;
  }
}

// ---------------------------------------------------------------------------
// k_cellsum: one wave per cell; pre-resolve sorted indices, __shfl-broadcast,
// 4-wide unrolled H-row loads so loads issue back-to-back.
// ---------------------------------------------------------------------------
__global__ __launch_bounds__(256) void k_cellsum(
    const u16* __restrict__ H, const int* __restrict__ sorted,
    const int* __restrict__ offs, u16* __restrict__ CS, int M) {
  const int lane = threadIdx.x & 63, wid = threadIdx.x >> 6;
  int c = blockIdx.x * 4 + wid;
  if (c >= M) return;
  int s = offs[c], e = offs[c + 1];
  float a0 = 0.f, a1 = 0.f, a2 = 0.f, a3 = 0.f;
  for (int base = s; base < e; base += 64) {
    int cnt = e - base; if (cnt > 64) cnt = 64;
    int idx = sorted[base + (lane < cnt ? lane : 0)];
    int j = 0;
    for (; j + 4 <= cnt; j += 4) {
      int n0 = __shfl(idx, j), n1 = __shfl(idx, j + 1);
      int n2 = __shfl(idx, j + 2), n3 = __shfl(idx, j + 3);
      ushort4 h0 = *(const ushort4*)(H + (size_t)n0 * 256 + lane * 4);
      ushort4 h1 = *(const ushort4*)(H + (size_t)n1 * 256 + lane * 4);
      ushort4 h2 = *(const ushort4*)(H + (size_t)n2 * 256 + lane * 4);
      ushort4 h3 = *(const ushort4*)(H + (size_t)n3 * 256 + lane * 4);
      a0 += bf2f(h0.x) + bf2f(h1.x) + bf2f(h2.x) + bf2f(h3.x);
      a1 += bf2f(h0.y) + bf2f(h1.y) + bf2f(h2.y) + bf2f(h3.y);
      a2 += bf2f(h0.z) + bf2f(h1.z) + bf2f(h2.z) + bf2f(h3.z);
      a3 += bf2f(h0.w) + bf2f(h1.w) + bf2f(h2.w) + bf2f(h3.w);
    }
    for (; j < cnt; ++j) {
      int nd = __shfl(idx, j);
      ushort4 h = *(const ushort4*)(H + (size_t)nd * 256 + lane * 4);
      a0 += bf2f(h.x); a1 += bf2f(h.y); a2 += bf2f(h.z); a3 += bf2f(h.w);
    }
  }
  ushort4 o;
  o.x = f2bf(a0); o.y = f2bf(a1); o.z = f2bf(a2); o.w = f2bf(a3);
  *(ushort4*)(CS + (size_t)c * 256 + lane * 4) = o;
}

// ---------------------------------------------------------------------------
// k_rho: OUT = relu(relu(CS@R1+c1)@R2+c2)@R3+c3. 128 rows/block, single
// 64KB LDS buffer, acc reused across the 3 layers, NT fp32 output stores.
// ---------------------------------------------------------------------------
__global__ __launch_bounds__(256) void k_rho(
    const u16* __restrict__ CS,
    const u16* __restrict__ R1s, const float* __restrict__ c1,
    const u16* __restrict__ R2s, const float* __restrict__ c2,
    const u16* __restrict__ R3s, const float* __restrict__ c3,
    float* __restrict__ OUT, int M) {
  __shared__ __align__(16) u16 buf[128 * 256];
  const int tid = threadIdx.x, lane = tid & 63, wid = tid >> 6;
  const int g = lane >> 4, r16 = lane & 15;
  const int rbase = blockIdx.x * 128;

  const u16* w1p = R1s + (size_t)(wid * 4) * 512 + lane * 8;
  const u16* w2p = R2s + (size_t)(wid * 4) * 512 + lane * 8;
  const u16* w3p = R3s + (size_t)(wid * 4) * 512 + lane * 8;

  // stage CS tile (already bf16)
#pragma unroll 8
  for (int it = 0; it < 16; ++it) {
    int u = it * 256 + tid;
    int row = u >> 5, k8 = u & 31;
    int crow = rbase + row; crow = crow < M ? crow : M - 1;
    uint4 d = *(const uint4*)(CS + (size_t)crow * 256 + k8 * 8);
    *(uint4*)(buf + row * 256 + ((k8 * 8) ^ ((row & 15) << 3))) = d;
  }
  __syncthreads();

  f32x4 acc[8][4];

  // ---- layer 1 ----
#pragma unroll
  for (int m = 0; m < 8; ++m)
#pragma unroll
    for (int n = 0; n < 4; ++n) acc[m][n] = (f32x4){0.f, 0.f, 0.f, 0.f};
#pragma unroll
  for (int ks = 0; ks < 8; ++ks) {
    bf16x8 bfr[4];
#pragma unroll
    for (int n = 0; n < 4; ++n)
      bfr[n] = *(const bf16x8*)(w1p + (size_t)ks * 8192 + n * 512);
#pragma unroll
    for (int m = 0; m < 8; ++m) {
      int row = m * 16 + r16;
      bf16x8 af = *(const bf16x8*)(buf + row * 256 + ((ks * 32 + g * 8) ^ (r16 << 3)));
#pragma unroll
      for (int n = 0; n < 4; ++n)
        acc[m][n] = __builtin_amdgcn_mfma_f32_16x16x32_bf16(af, bfr[n], acc[m][n], 0, 0, 0);
    }
  }
  __syncthreads();  // done reading CS tile

  float bias1[4];
#pragma unroll
  for (int n = 0; n < 4; ++n) bias1[n] = c1[wid * 64 + n * 16 + r16];
#pragma unroll
  for (int m = 0; m < 8; ++m)
#pragma unroll
    for (int n = 0; n < 4; ++n)
#pragma unroll
      for (int rr = 0; rr < 4; ++rr) {
        int row = m * 16 + g * 4 + rr;
        int col = wid * 64 + n * 16 + r16;
        float v = fmaxf(acc[m][n][rr] + bias1[n], 0.f);
        buf[row * 256 + (col ^ ((row & 15) << 3))] = f2bf(v);
      }
  __syncthreads();

  // ---- layer 2 ----
#pragma unroll
  for (int m = 0; m < 8; ++m)
#pragma unroll
    for (int n = 0; n < 4; ++n) acc[m][n] = (f32x4){0.f, 0.f, 0.f, 0.f};
#pragma unroll
  for (int ks = 0; ks < 8; ++ks) {
    bf16x8 bfr[4];
#pragma unroll
    for (int n = 0; n < 4; ++n)
      bfr[n] = *(const bf16x8*)(w2p + (size_t)ks * 8192 + n * 512);
#pragma unroll
    for (int m = 0; m < 8; ++m) {
      int row = m * 16 + r16;
      bf16x8 af = *(const bf16x8*)(buf + row * 256 + ((ks * 32 + g * 8) ^ (r16 << 3)));
#pragma unroll
      for (int n = 0; n < 4; ++n)
        acc[m][n] = __builtin_amdgcn_mfma_f32_16x16x32_bf16(af, bfr[n], acc[m][n], 0, 0, 0);
    }
  }
  __syncthreads();  // done reading h1

  float bias2[4];
#pragma unroll
  for (int n = 0; n < 4; ++n) bias2[n] = c2[wid * 64 + n * 16 + r16];
#pragma unroll
  for (int m = 0; m < 8; ++m)
#pragma unroll
    for (int n = 0; n < 4; ++n)
#pragma unroll
      for (int rr = 0; rr < 4; ++rr) {
        int row = m * 16 + g * 4 + rr;
        int col = wid * 64 + n * 16 + r16;
        float v = fmaxf(acc[m][n][rr] + bias2[n], 0.f);
        buf[row * 256 + (col ^ ((row & 15) << 3))] = f2bf(v);
      }
  __syncthreads();

  // ---- layer 3 (no relu), NT fp32 stores ----
#pragma unroll
  for (int m = 0; m < 8; ++m)
#pragma unroll
    for (int n = 0; n < 4; ++n) acc[m][n] = (f32x4){0.f, 0.f, 0.f, 0.f};
#pragma unroll
  for (int ks = 0; ks < 8; ++ks) {
    bf16x8 bfr[4];
#pragma unroll
    for (int n = 0; n < 4; ++n)
      bfr[n] = *(const bf16x8*)(w3p + (size_t)ks * 8192 + n * 512);
#pragma unroll
    for (int m = 0; m < 8; ++m) {
      int row = m * 16 + r16;
      bf16x8 af = *(const bf16x8*)(buf + row * 256 + ((ks * 32 + g * 8) ^ (r16 << 3)));
#pragma unroll
      for (int n = 0; n < 4; ++n)
        acc[m][n] = __builtin_amdgcn_mfma_f32_16x16x32_bf16(af, bfr[n], acc[m][n], 0, 0, 0);
    }
  }
#pragma unroll
  for (int n = 0; n < 4; ++n) {
    float bias = c3[wid * 64 + n * 16 + r16];
#pragma unroll
    for (int m = 0; m < 8; ++m)
#pragma unroll
      for (int rr = 0; rr < 4; ++rr) {
        int grow = rbase + m * 16 + g * 4 + rr;
        if (grow < M)
          __builtin_nontemporal_store(acc[m][n][rr] + bias,
                                      OUT + (size_t)grow * 256 + wid * 64 + n * 16 + r16);
      }
  }
}

// ---------------------------------------------------------------------------
extern "C" void kernel_launch(void* const* d_in, const int* in_sizes, int n_in,
                              void* d_out, int out_size, void* d_ws, size_t ws_size,
                              hipStream_t stream) {
  const float* X    = (const float*)d_in[0];
  const int* nodes  = (const int*)d_in[1];
  const int* cells  = (const int*)d_in[2];
  const float* W1   = (const float*)d_in[4];
  const float* b1   = (const float*)d_in[5];
  const float* W2   = (const float*)d_in[6];
  const float* b2   = (const float*)d_in[7];
  const float* R1   = (const float*)d_in[8];
  const float* c1   = (const float*)d_in[9];
  const float* R2   = (const float*)d_in[10];
  const float* c2   = (const float*)d_in[11];
  const float* R3   = (const float*)d_in[12];
  const float* c3   = (const float*)d_in[13];
  float* OUT = (float*)d_out;

  const int N = in_sizes[0] / 384;   // 100000
  const int E = in_sizes[1];         // 400000
  const int M = out_size / 256;      // 50000

  char* ws = (char*)d_ws;
  size_t off = 0;
  auto alloc = [&](size_t b) { size_t o = off; off += (b + 255) & ~(size_t)255; return o; };
  u16* W1s    = (u16*)(ws + alloc((size_t)12 * 16 * 64 * 8 * 2));
  u16* W2s    = (u16*)(ws + alloc((size_t)8 * 16 * 64 * 8 * 2));
  u16* R1s    = (u16*)(ws + alloc((size_t)8 * 16 * 64 * 8 * 2));
  u16* R2s    = (u16*)(ws + alloc((size_t)8 * 16 * 64 * 8 * 2));
  u16* R3s    = (u16*)(ws + alloc((size_t)8 * 16 * 64 * 8 * 2));
  u16* H      = (u16*)(ws + alloc((size_t)N * 256 * 2));
  u16* CS     = (u16*)(ws + alloc((size_t)M * 256 * 2));
  int* counts = (int*)(ws + alloc((size_t)M * 4));
  int* offs   = (int*)(ws + alloc((size_t)(M + 1) * 4));
  int* cursor = (int*)(ws + alloc((size_t)M * 4));
  int* sorted = (int*)(ws + alloc((size_t)E * 4));
  int* bsum   = (int*)(ws + alloc((size_t)256 * 4));

  const int NB = (M + 255) / 256;

  hipMemsetAsync(counts, 0, (size_t)M * 4, stream);
  k_prep<<<176, 256, 0, stream>>>(W1, W2, R1, R2, R3, W1s, W2s, R1s, R2s, R3s);
  k_hist<<<(E + 255) / 256, 256, 0, stream>>>(cells, counts, E);
  k_scan1<<<NB, 256, 0, stream>>>(counts, offs, bsum, M);
  k_scan2<<<1, 256, 0, stream>>>(bsum, NB);
  k_scan3<<<(M + 256) / 256, 256, 0, stream>>>(offs, bsum, cursor, M, E);
  k_scatter<<<(E + 255) / 256, 256, 0, stream>>>(cells, nodes, cursor, sorted, E);
  k_phi<<<(N + 127) / 128, 256, 0, stream>>>(X, W1s, b1, W2s, b2, H, N);
  k_cellsum<<<(M + 3) / 4, 256, 0, stream>>>(H, sorted, offs, CS, M);
  k_rho<<<(M + 127) / 128, 256, 0, stream>>>(CS, R1s, c1, R2s, c2, R3s, c3, OUT, M);
}

// Round 6
// 224.181 us; speedup vs baseline: 1.1564x; 1.1564x over previous
//
#include <hip/hip_runtime.h>

typedef unsigned short u16;
typedef __bf16 bf16x8 __attribute__((ext_vector_type(8)));
typedef float f32x4 __attribute__((ext_vector_type(4)));

__device__ __forceinline__ u16 f2bf(float f) {
  unsigned int u = __builtin_bit_cast(unsigned int, f);
  u += 0x7fffu + ((u >> 16) & 1u);
  return (u16)(u >> 16);
}
__device__ __forceinline__ float bf2f(u16 h) {
  unsigned int u = ((unsigned int)h) << 16;
  return __builtin_bit_cast(float, u);
}

// ---------------------------------------------------------------------------
// k_prep: fp32 weights -> bf16 MFMA B-fragment order.
// Fragment (ks, nt, lane): 8 elems W[ks*32 + (lane>>4)*8 + j][nt*16 + (lane&15)]
// at dst[((ks*16+nt)*64 + lane)*8 + j].
// ---------------------------------------------------------------------------
__global__ __launch_bounds__(256) void k_prep(
    const float* __restrict__ W1, const float* __restrict__ W2,
    const float* __restrict__ R1, const float* __restrict__ R2, const float* __restrict__ R3,
    u16* __restrict__ W1s, u16* __restrict__ W2s,
    u16* __restrict__ R1s, u16* __restrict__ R2s, u16* __restrict__ R3s) {
  int t = blockIdx.x * 256 + threadIdx.x;
  const float* src; u16* dst; int lt;
  if (t < 12288) { src = W1; dst = W1s; lt = t; }
  else {
    int u = t - 12288;
    int m = u >> 13;
    lt = u & 8191;
    if (m == 0)      { src = W2; dst = W2s; }
    else if (m == 1) { src = R1; dst = R1s; }
    else if (m == 2) { src = R2; dst = R2s; }
    else if (m == 3) { src = R3; dst = R3s; }
    else return;
  }
  int lane = lt & 63;
  int nt = (lt >> 6) & 15;
  int ks = lt >> 10;
  int col = nt * 16 + (lane & 15);
  int kb = ks * 32 + (lane >> 4) * 8;
  union { u16 u[8]; uint4 v; } o;
#pragma unroll
  for (int j = 0; j < 8; ++j) o.u[j] = f2bf(src[(size_t)(kb + j) * 256 + col]);
  *(uint4*)(dst + (size_t)lt * 8) = o.v;
}

// ---------------------------------------------------------------------------
// CSR build: histogram -> 3-stage multi-block exclusive scan -> scatter.
// ---------------------------------------------------------------------------
__global__ __launch_bounds__(256) void k_hist(const int* __restrict__ cells,
                                              int* __restrict__ counts, int E) {
  int e = blockIdx.x * 256 + threadIdx.x;
  if (e < E) atomicAdd(&counts[cells[e]], 1);
}

__global__ __launch_bounds__(256) void k_scan1(const int* __restrict__ counts,
                                               int* __restrict__ offs,
                                               int* __restrict__ bsum, int M) {
  __shared__ int ws[4];
  int tid = threadIdx.x, lane = tid & 63, wid = tid >> 6;
  int i = blockIdx.x * 256 + tid;
  int v = (i < M) ? counts[i] : 0;
  int x = v;
#pragma unroll
  for (int s = 1; s < 64; s <<= 1) { int y = __shfl_up(x, s); if (lane >= s) x += y; }
  if (lane == 63) ws[wid] = x;
  __syncthreads();
  int pre = 0;
#pragma unroll
  for (int w = 0; w < 4; ++w) if (w < wid) pre += ws[w];
  if (i < M) offs[i] = pre + x - v;
  if (tid == 255) bsum[blockIdx.x] = pre + x;
}

__global__ __launch_bounds__(256) void k_scan2(int* __restrict__ bsum, int nb) {
  __shared__ int ws[4];
  int tid = threadIdx.x, lane = tid & 63, wid = tid >> 6;
  int v = (tid < nb) ? bsum[tid] : 0;
  int x = v;
#pragma unroll
  for (int s = 1; s < 64; s <<= 1) { int y = __shfl_up(x, s); if (lane >= s) x += y; }
  if (lane == 63) ws[wid] = x;
  __syncthreads();
  int pre = 0;
#pragma unroll
  for (int w = 0; w < 4; ++w) if (w < wid) pre += ws[w];
  if (tid < nb) bsum[tid] = pre + x - v;
}

__global__ __launch_bounds__(256) void k_scan3(int* __restrict__ offs,
                                               const int* __restrict__ bsum,
                                               int* __restrict__ cursor, int M, int E) {
  int i = blockIdx.x * 256 + threadIdx.x;
  if (i < M) { int o = offs[i] + bsum[blockIdx.x]; offs[i] = o; cursor[i] = o; }
  if (i == M) offs[M] = E;
}

__global__ __launch_bounds__(256) void k_scatter(const int* __restrict__ cells,
                                                 const int* __restrict__ nodes,
                                                 int* __restrict__ cursor,
                                                 int* __restrict__ sorted, int E) {
  int e = blockIdx.x * 256 + threadIdx.x;
  if (e < E) {
    int c = cells[e];
    int p = atomicAdd(&cursor[c], 1);
    sorted[p] = nodes[e];
  }
}

// ---------------------------------------------------------------------------
// k_phi: H = relu(relu(X@W1+b1)@W2+b2). 64 rows/block, 4 waves; wave w owns
// cols [w*64, w*64+64). Single 32KB LDS buffer (XOR swizzle ^((row&15)<<3)).
// ks-loops ROLLED (#pragma unroll 1) so the kernel body fits I$ — only the
// acc-indexed m/n loops stay unrolled (static register indexing).
// ---------------------------------------------------------------------------
__global__ __launch_bounds__(256) void k_phi(
    const float* __restrict__ X,
    const u16* __restrict__ W1s, const float* __restrict__ b1,
    const u16* __restrict__ W2s, const float* __restrict__ b2,
    u16* __restrict__ H, int N) {
  __shared__ __align__(16) u16 buf[64 * 256];
  const int tid = threadIdx.x, lane = tid & 63, wid = tid >> 6;
  const int g = lane >> 4, r16 = lane & 15;
  const int rbase = blockIdx.x * 64;
  const int swz = r16 << 3;  // u16-unit XOR for this thread's A-reads

  const u16* w1p = W1s + (size_t)(wid * 4) * 512 + lane * 8;  // + ks*8192 + n*512
  const u16* w2p = W2s + (size_t)(wid * 4) * 512 + lane * 8;

  // ---- stage phase 0: X cols [0,256) ----
#pragma unroll 4
  for (int it = 0; it < 16; ++it) {
    int u = it * 256 + tid;
    int row = u >> 6, c4 = u & 63;
    int crow = rbase + row; crow = crow < N ? crow : N - 1;
    f32x4 v = *(const f32x4*)(X + (size_t)crow * 384 + c4 * 4);
    uint2 pk;
    pk.x = (unsigned int)f2bf(v[0]) | ((unsigned int)f2bf(v[1]) << 16);
    pk.y = (unsigned int)f2bf(v[2]) | ((unsigned int)f2bf(v[3]) << 16);
    *(uint2*)(buf + row * 256 + ((c4 * 4) ^ ((row & 15) << 3))) = pk;
  }
  __syncthreads();

  f32x4 acc[4][4];
#pragma unroll
  for (int m = 0; m < 4; ++m)
#pragma unroll
    for (int n = 0; n < 4; ++n) acc[m][n] = (f32x4){0.f, 0.f, 0.f, 0.f};

  // ---- layer 1, K phase 0 (ks 0..7), rolled ----
#pragma unroll 1
  for (int ks = 0; ks < 8; ++ks) {
    bf16x8 bfr[4];
#pragma unroll
    for (int n = 0; n < 4; ++n)
      bfr[n] = *(const bf16x8*)(w1p + (size_t)ks * 8192 + n * 512);
    const u16* bp = buf + ((ks * 32 + g * 8) ^ swz);
#pragma unroll
    for (int m = 0; m < 4; ++m) {
      bf16x8 af = *(const bf16x8*)(bp + (m * 16 + r16) * 256);
#pragma unroll
      for (int n = 0; n < 4; ++n)
        acc[m][n] = __builtin_amdgcn_mfma_f32_16x16x32_bf16(af, bfr[n], acc[m][n], 0, 0, 0);
    }
  }
  __syncthreads();  // done reading phase-0 A

  // ---- stage phase 1: X cols [256,384) into buf u16-cols [0,128) ----
#pragma unroll 4
  for (int it = 0; it < 8; ++it) {
    int u = it * 256 + tid;
    int row = u >> 5, c4 = u & 31;
    int crow = rbase + row; crow = crow < N ? crow : N - 1;
    f32x4 v = *(const f32x4*)(X + (size_t)crow * 384 + 256 + c4 * 4);
    uint2 pk;
    pk.x = (unsigned int)f2bf(v[0]) | ((unsigned int)f2bf(v[1]) << 16);
    pk.y = (unsigned int)f2bf(v[2]) | ((unsigned int)f2bf(v[3]) << 16);
    *(uint2*)(buf + row * 256 + ((c4 * 4) ^ ((row & 15) << 3))) = pk;
  }
  __syncthreads();

  // ---- layer 1, K phase 1 (ks 8..11), rolled ----
#pragma unroll 1
  for (int ksl = 0; ksl < 4; ++ksl) {
    bf16x8 bfr[4];
#pragma unroll
    for (int n = 0; n < 4; ++n)
      bfr[n] = *(const bf16x8*)(w1p + (size_t)(8 + ksl) * 8192 + n * 512);
    const u16* bp = buf + ((ksl * 32 + g * 8) ^ swz);
#pragma unroll
    for (int m = 0; m < 4; ++m) {
      bf16x8 af = *(const bf16x8*)(bp + (m * 16 + r16) * 256);
#pragma unroll
      for (int n = 0; n < 4; ++n)
        acc[m][n] = __builtin_amdgcn_mfma_f32_16x16x32_bf16(af, bfr[n], acc[m][n], 0, 0, 0);
    }
  }
  __syncthreads();  // done reading phase-1 A; buf free for h1

  // ---- h1 = relu(acc + b1) -> buf (acc-indexed: stays unrolled) ----
  float bias1[4];
#pragma unroll
  for (int n = 0; n < 4; ++n) bias1[n] = b1[wid * 64 + n * 16 + r16];
#pragma unroll
  for (int m = 0; m < 4; ++m)
#pragma unroll
    for (int n = 0; n < 4; ++n)
#pragma unroll
      for (int rr = 0; rr < 4; ++rr) {
        int row = m * 16 + g * 4 + rr;
        int col = wid * 64 + n * 16 + r16;
        float v = fmaxf(acc[m][n][rr] + bias1[n], 0.f);
        buf[row * 256 + (col ^ ((row & 15) << 3))] = f2bf(v);
      }
  __syncthreads();

  // ---- layer 2 (reuse acc), rolled ----
#pragma unroll
  for (int m = 0; m < 4; ++m)
#pragma unroll
    for (int n = 0; n < 4; ++n) acc[m][n] = (f32x4){0.f, 0.f, 0.f, 0.f};
#pragma unroll 1
  for (int ks = 0; ks < 8; ++ks) {
    bf16x8 bfr[4];
#pragma unroll
    for (int n = 0; n < 4; ++n)
      bfr[n] = *(const bf16x8*)(w2p + (size_t)ks * 8192 + n * 512);
    const u16* bp = buf + ((ks * 32 + g * 8) ^ swz);
#pragma unroll
    for (int m = 0; m < 4; ++m) {
      bf16x8 af = *(const bf16x8*)(bp + (m * 16 + r16) * 256);
#pragma unroll
      for (int n = 0; n < 4; ++n)
        acc[m][n] = __builtin_amdgcn_mfma_f32_16x16x32_bf16(af, bfr[n], acc[m][n], 0, 0, 0);
    }
  }
  __syncthreads();  // done reading h1

  // ---- h2 = relu(acc + b2) -> buf ----
  float bias2[4];
#pragma unroll
  for (int n = 0; n < 4; ++n) bias2[n] = b2[wid * 64 + n * 16 + r16];
#pragma unroll
  for (int m = 0; m < 4; ++m)
#pragma unroll
    for (int n = 0; n < 4; ++n)
#pragma unroll
      for (int rr = 0; rr < 4; ++rr) {
        int row = m * 16 + g * 4 + rr;
        int col = wid * 64 + n * 16 + r16;
        float v = fmaxf(acc[m][n][rr] + bias2[n], 0.f);
        buf[row * 256 + (col ^ ((row & 15) << 3))] = f2bf(v);
      }
  __syncthreads();

  // ---- coalesced copy out ----
#pragma unroll 4
  for (int it = 0; it < 8; ++it) {
    int u = it * 256 + tid;
    int row = u >> 5, k8 = u & 31;
    uint4 d = *(const uint4*)(buf + row * 256 + ((k8 * 8) ^ ((row & 15) << 3)));
    int grow = rbase + row;
    if (grow < N) *(uint4*)(H + (size_t)grow * 256 + k8 * 8) = d;
  }
}

// ---------------------------------------------------------------------------
// k_cellsum: one wave per cell; pre-resolve sorted indices, __shfl-broadcast,
// 4-wide unrolled H-row loads so loads issue back-to-back.
// ---------------------------------------------------------------------------
__global__ __launch_bounds__(256) void k_cellsum(
    const u16* __restrict__ H, const int* __restrict__ sorted,
    const int* __restrict__ offs, u16* __restrict__ CS, int M) {
  const int lane = threadIdx.x & 63, wid = threadIdx.x >> 6;
  int c = blockIdx.x * 4 + wid;
  if (c >= M) return;
  int s = offs[c], e = offs[c + 1];
  float a0 = 0.f, a1 = 0.f, a2 = 0.f, a3 = 0.f;
  for (int base = s; base < e; base += 64) {
    int cnt = e - base; if (cnt > 64) cnt = 64;
    int idx = sorted[base + (lane < cnt ? lane : 0)];
    int j = 0;
    for (; j + 4 <= cnt; j += 4) {
      int n0 = __shfl(idx, j), n1 = __shfl(idx, j + 1);
      int n2 = __shfl(idx, j + 2), n3 = __shfl(idx, j + 3);
      ushort4 h0 = *(const ushort4*)(H + (size_t)n0 * 256 + lane * 4);
      ushort4 h1 = *(const ushort4*)(H + (size_t)n1 * 256 + lane * 4);
      ushort4 h2 = *(const ushort4*)(H + (size_t)n2 * 256 + lane * 4);
      ushort4 h3 = *(const ushort4*)(H + (size_t)n3 * 256 + lane * 4);
      a0 += bf2f(h0.x) + bf2f(h1.x) + bf2f(h2.x) + bf2f(h3.x);
      a1 += bf2f(h0.y) + bf2f(h1.y) + bf2f(h2.y) + bf2f(h3.y);
      a2 += bf2f(h0.z) + bf2f(h1.z) + bf2f(h2.z) + bf2f(h3.z);
      a3 += bf2f(h0.w) + bf2f(h1.w) + bf2f(h2.w) + bf2f(h3.w);
    }
    for (; j < cnt; ++j) {
      int nd = __shfl(idx, j);
      ushort4 h = *(const ushort4*)(H + (size_t)nd * 256 + lane * 4);
      a0 += bf2f(h.x); a1 += bf2f(h.y); a2 += bf2f(h.z); a3 += bf2f(h.w);
    }
  }
  ushort4 o;
  o.x = f2bf(a0); o.y = f2bf(a1); o.z = f2bf(a2); o.w = f2bf(a3);
  *(ushort4*)(CS + (size_t)c * 256 + lane * 4) = o;
}

// ---------------------------------------------------------------------------
// k_rho: OUT = relu(relu(CS@R1+c1)@R2+c2)@R3+c3. 64 rows/block, single 32KB
// LDS buffer, rolled ks-loops (small code), fp32 direct stores.
// ---------------------------------------------------------------------------
__global__ __launch_bounds__(256) void k_rho(
    const u16* __restrict__ CS,
    const u16* __restrict__ R1s, const float* __restrict__ c1,
    const u16* __restrict__ R2s, const float* __restrict__ c2,
    const u16* __restrict__ R3s, const float* __restrict__ c3,
    float* __restrict__ OUT, int M) {
  __shared__ __align__(16) u16 buf[64 * 256];
  const int tid = threadIdx.x, lane = tid & 63, wid = tid >> 6;
  const int g = lane >> 4, r16 = lane & 15;
  const int rbase = blockIdx.x * 64;
  const int swz = r16 << 3;

  const u16* w1p = R1s + (size_t)(wid * 4) * 512 + lane * 8;
  const u16* w2p = R2s + (size_t)(wid * 4) * 512 + lane * 8;
  const u16* w3p = R3s + (size_t)(wid * 4) * 512 + lane * 8;

  // stage CS tile (already bf16)
#pragma unroll 4
  for (int it = 0; it < 8; ++it) {
    int u = it * 256 + tid;
    int row = u >> 5, k8 = u & 31;
    int crow = rbase + row; crow = crow < M ? crow : M - 1;
    uint4 d = *(const uint4*)(CS + (size_t)crow * 256 + k8 * 8);
    *(uint4*)(buf + row * 256 + ((k8 * 8) ^ ((row & 15) << 3))) = d;
  }
  __syncthreads();

  f32x4 acc[4][4];

  // ---- layer 1, rolled ----
#pragma unroll
  for (int m = 0; m < 4; ++m)
#pragma unroll
    for (int n = 0; n < 4; ++n) acc[m][n] = (f32x4){0.f, 0.f, 0.f, 0.f};
#pragma unroll 1
  for (int ks = 0; ks < 8; ++ks) {
    bf16x8 bfr[4];
#pragma unroll
    for (int n = 0; n < 4; ++n)
      bfr[n] = *(const bf16x8*)(w1p + (size_t)ks * 8192 + n * 512);
    const u16* bp = buf + ((ks * 32 + g * 8) ^ swz);
#pragma unroll
    for (int m = 0; m < 4; ++m) {
      bf16x8 af = *(const bf16x8*)(bp + (m * 16 + r16) * 256);
#pragma unroll
      for (int n = 0; n < 4; ++n)
        acc[m][n] = __builtin_amdgcn_mfma_f32_16x16x32_bf16(af, bfr[n], acc[m][n], 0, 0, 0);
    }
  }
  __syncthreads();  // done reading CS tile

  float bias1[4];
#pragma unroll
  for (int n = 0; n < 4; ++n) bias1[n] = c1[wid * 64 + n * 16 + r16];
#pragma unroll
  for (int m = 0; m < 4; ++m)
#pragma unroll
    for (int n = 0; n < 4; ++n)
#pragma unroll
      for (int rr = 0; rr < 4; ++rr) {
        int row = m * 16 + g * 4 + rr;
        int col = wid * 64 + n * 16 + r16;
        float v = fmaxf(acc[m][n][rr] + bias1[n], 0.f);
        buf[row * 256 + (col ^ ((row & 15) << 3))] = f2bf(v);
      }
  __syncthreads();

  // ---- layer 2, rolled ----
#pragma unroll
  for (int m = 0; m < 4; ++m)
#pragma unroll
    for (int n = 0; n < 4; ++n) acc[m][n] = (f32x4){0.f, 0.f, 0.f, 0.f};
#pragma unroll 1
  for (int ks = 0; ks < 8; ++ks) {
    bf16x8 bfr[4];
#pragma unroll
    for (int n = 0; n < 4; ++n)
      bfr[n] = *(const bf16x8*)(w2p + (size_t)ks * 8192 + n * 512);
    const u16* bp = buf + ((ks * 32 + g * 8) ^ swz);
#pragma unroll
    for (int m = 0; m < 4; ++m) {
      bf16x8 af = *(const bf16x8*)(bp + (m * 16 + r16) * 256);
#pragma unroll
      for (int n = 0; n < 4; ++n)
        acc[m][n] = __builtin_amdgcn_mfma_f32_16x16x32_bf16(af, bfr[n], acc[m][n], 0, 0, 0);
    }
  }
  __syncthreads();  // done reading h1

  float bias2[4];
#pragma unroll
  for (int n = 0; n < 4; ++n) bias2[n] = c2[wid * 64 + n * 16 + r16];
#pragma unroll
  for (int m = 0; m < 4; ++m)
#pragma unroll
    for (int n = 0; n < 4; ++n)
#pragma unroll
      for (int rr = 0; rr < 4; ++rr) {
        int row = m * 16 + g * 4 + rr;
        int col = wid * 64 + n * 16 + r16;
        float v = fmaxf(acc[m][n][rr] + bias2[n], 0.f);
        buf[row * 256 + (col ^ ((row & 15) << 3))] = f2bf(v);
      }
  __syncthreads();

  // ---- layer 3 (no relu), rolled, direct fp32 stores ----
#pragma unroll
  for (int m = 0; m < 4; ++m)
#pragma unroll
    for (int n = 0; n < 4; ++n) acc[m][n] = (f32x4){0.f, 0.f, 0.f, 0.f};
#pragma unroll 1
  for (int ks = 0; ks < 8; ++ks) {
    bf16x8 bfr[4];
#pragma unroll
    for (int n = 0; n < 4; ++n)
      bfr[n] = *(const bf16x8*)(w3p + (size_t)ks * 8192 + n * 512);
    const u16* bp = buf + ((ks * 32 + g * 8) ^ swz);
#pragma unroll
    for (int m = 0; m < 4; ++m) {
      bf16x8 af = *(const bf16x8*)(bp + (m * 16 + r16) * 256);
#pragma unroll
      for (int n = 0; n < 4; ++n)
        acc[m][n] = __builtin_amdgcn_mfma_f32_16x16x32_bf16(af, bfr[n], acc[m][n], 0, 0, 0);
    }
  }
#pragma unroll
  for (int n = 0; n < 4; ++n) {
    float bias = c3[wid * 64 + n * 16 + r16];
#pragma unroll
    for (int m = 0; m < 4; ++m)
#pragma unroll
      for (int rr = 0; rr < 4; ++rr) {
        int grow = rbase + m * 16 + g * 4 + rr;
        if (grow < M) OUT[(size_t)grow * 256 + wid * 64 + n * 16 + r16] = acc[m][n][rr] + bias;
      }
  }
}

// ---------------------------------------------------------------------------
extern "C" void kernel_launch(void* const* d_in, const int* in_sizes, int n_in,
                              void* d_out, int out_size, void* d_ws, size_t ws_size,
                              hipStream_t stream) {
  const float* X    = (const float*)d_in[0];
  const int* nodes  = (const int*)d_in[1];
  const int* cells  = (const int*)d_in[2];
  const float* W1   = (const float*)d_in[4];
  const float* b1   = (const float*)d_in[5];
  const float* W2   = (const float*)d_in[6];
  const float* b2   = (const float*)d_in[7];
  const float* R1   = (const float*)d_in[8];
  const float* c1   = (const float*)d_in[9];
  const float* R2   = (const float*)d_in[10];
  const float* c2   = (const float*)d_in[11];
  const float* R3   = (const float*)d_in[12];
  const float* c3   = (const float*)d_in[13];
  float* OUT = (float*)d_out;

  const int N = in_sizes[0] / 384;   // 100000
  const int E = in_sizes[1];         // 400000
  const int M = out_size / 256;      // 50000

  char* ws = (char*)d_ws;
  size_t off = 0;
  auto alloc = [&](size_t b) { size_t o = off; off += (b + 255) & ~(size_t)255; return o; };
  u16* W1s    = (u16*)(ws + alloc((size_t)12 * 16 * 64 * 8 * 2));
  u16* W2s    = (u16*)(ws + alloc((size_t)8 * 16 * 64 * 8 * 2));
  u16* R1s    = (u16*)(ws + alloc((size_t)8 * 16 * 64 * 8 * 2));
  u16* R2s    = (u16*)(ws + alloc((size_t)8 * 16 * 64 * 8 * 2));
  u16* R3s    = (u16*)(ws + alloc((size_t)8 * 16 * 64 * 8 * 2));
  u16* H      = (u16*)(ws + alloc((size_t)N * 256 * 2));
  u16* CS     = (u16*)(ws + alloc((size_t)M * 256 * 2));
  int* counts = (int*)(ws + alloc((size_t)M * 4));
  int* offs   = (int*)(ws + alloc((size_t)(M + 1) * 4));
  int* cursor = (int*)(ws + alloc((size_t)M * 4));
  int* sorted = (int*)(ws + alloc((size_t)E * 4));
  int* bsum   = (int*)(ws + alloc((size_t)256 * 4));

  const int NB = (M + 255) / 256;

  hipMemsetAsync(counts, 0, (size_t)M * 4, stream);
  k_prep<<<176, 256, 0, stream>>>(W1, W2, R1, R2, R3, W1s, W2s, R1s, R2s, R3s);
  k_hist<<<(E + 255) / 256, 256, 0, stream>>>(cells, counts, E);
  k_scan1<<<NB, 256, 0, stream>>>(counts, offs, bsum, M);
  k_scan2<<<1, 256, 0, stream>>>(bsum, NB);
  k_scan3<<<(M + 256) / 256, 256, 0, stream>>>(offs, bsum, cursor, M, E);
  k_scatter<<<(E + 255) / 256, 256, 0, stream>>>(cells, nodes, cursor, sorted, E);
  k_phi<<<(N + 63) / 64, 256, 0, stream>>>(X, W1s, b1, W2s, b2, H, N);
  k_cellsum<<<(M + 3) / 4, 256, 0, stream>>>(H, sorted, offs, CS, M);
  k_rho<<<(M + 63) / 64, 256, 0, stream>>>(CS, R1s, c1, R2s, c2, R3s, c3, OUT, M);
}

// Round 7
// 221.988 us; speedup vs baseline: 1.1679x; 1.0099x over previous
//
#include <hip/hip_runtime.h>

typedef unsigned short u16;
typedef __bf16 bf16x8 __attribute__((ext_vector_type(8)));
typedef float f32x4 __attribute__((ext_vector_type(4)));

__device__ __forceinline__ u16 f2bf(float f) {
  unsigned int u = __builtin_bit_cast(unsigned int, f);
  u += 0x7fffu + ((u >> 16) & 1u);
  return (u16)(u >> 16);
}
__device__ __forceinline__ float bf2f(u16 h) {
  unsigned int u = ((unsigned int)h) << 16;
  return __builtin_bit_cast(float, u);
}

// ---------------------------------------------------------------------------
// k_prep: fp32 weights -> bf16 MFMA B-fragment order.
// Fragment (ks, nt, lane): 8 elems W[ks*32 + (lane>>4)*8 + j][nt*16 + (lane&15)]
// at dst[((ks*16+nt)*64 + lane)*8 + j].
// ---------------------------------------------------------------------------
__global__ __launch_bounds__(256) void k_prep(
    const float* __restrict__ W1, const float* __restrict__ W2,
    const float* __restrict__ R1, const float* __restrict__ R2, const float* __restrict__ R3,
    u16* __restrict__ W1s, u16* __restrict__ W2s,
    u16* __restrict__ R1s, u16* __restrict__ R2s, u16* __restrict__ R3s) {
  int t = blockIdx.x * 256 + threadIdx.x;
  const float* src; u16* dst; int lt;
  if (t < 12288) { src = W1; dst = W1s; lt = t; }
  else {
    int u = t - 12288;
    int m = u >> 13;
    lt = u & 8191;
    if (m == 0)      { src = W2; dst = W2s; }
    else if (m == 1) { src = R1; dst = R1s; }
    else if (m == 2) { src = R2; dst = R2s; }
    else if (m == 3) { src = R3; dst = R3s; }
    else return;
  }
  int lane = lt & 63;
  int nt = (lt >> 6) & 15;
  int ks = lt >> 10;
  int col = nt * 16 + (lane & 15);
  int kb = ks * 32 + (lane >> 4) * 8;
  union { u16 u[8]; uint4 v; } o;
#pragma unroll
  for (int j = 0; j < 8; ++j) o.u[j] = f2bf(src[(size_t)(kb + j) * 256 + col]);
  *(uint4*)(dst + (size_t)lt * 8) = o.v;
}

// ---------------------------------------------------------------------------
// CSR build: histogram -> 3-stage multi-block exclusive scan -> scatter.
// ---------------------------------------------------------------------------
__global__ __launch_bounds__(256) void k_hist(const int* __restrict__ cells,
                                              int* __restrict__ counts, int E) {
  int e = blockIdx.x * 256 + threadIdx.x;
  if (e < E) atomicAdd(&counts[cells[e]], 1);
}

__global__ __launch_bounds__(256) void k_scan1(const int* __restrict__ counts,
                                               int* __restrict__ offs,
                                               int* __restrict__ bsum, int M) {
  __shared__ int ws[4];
  int tid = threadIdx.x, lane = tid & 63, wid = tid >> 6;
  int i = blockIdx.x * 256 + tid;
  int v = (i < M) ? counts[i] : 0;
  int x = v;
#pragma unroll
  for (int s = 1; s < 64; s <<= 1) { int y = __shfl_up(x, s); if (lane >= s) x += y; }
  if (lane == 63) ws[wid] = x;
  __syncthreads();
  int pre = 0;
#pragma unroll
  for (int w = 0; w < 4; ++w) if (w < wid) pre += ws[w];
  if (i < M) offs[i] = pre + x - v;
  if (tid == 255) bsum[blockIdx.x] = pre + x;
}

__global__ __launch_bounds__(256) void k_scan2(int* __restrict__ bsum, int nb) {
  __shared__ int ws[4];
  int tid = threadIdx.x, lane = tid & 63, wid = tid >> 6;
  int v = (tid < nb) ? bsum[tid] : 0;
  int x = v;
#pragma unroll
  for (int s = 1; s < 64; s <<= 1) { int y = __shfl_up(x, s); if (lane >= s) x += y; }
  if (lane == 63) ws[wid] = x;
  __syncthreads();
  int pre = 0;
#pragma unroll
  for (int w = 0; w < 4; ++w) if (w < wid) pre += ws[w];
  if (tid < nb) bsum[tid] = pre + x - v;
}

__global__ __launch_bounds__(256) void k_scan3(int* __restrict__ offs,
                                               const int* __restrict__ bsum,
                                               int* __restrict__ cursor, int M, int E) {
  int i = blockIdx.x * 256 + threadIdx.x;
  if (i < M) { int o = offs[i] + bsum[blockIdx.x]; offs[i] = o; cursor[i] = o; }
  if (i == M) offs[M] = E;
}

__global__ __launch_bounds__(256) void k_scatter(const int* __restrict__ cells,
                                                 const int* __restrict__ nodes,
                                                 int* __restrict__ cursor,
                                                 int* __restrict__ sorted, int E) {
  int e = blockIdx.x * 256 + threadIdx.x;
  if (e < E) {
    int c = cells[e];
    int p = atomicAdd(&cursor[c], 1);
    sorted[p] = nodes[e];
  }
}

// ---------------------------------------------------------------------------
// k_phi: H = relu(relu(X@W1+b1)@W2+b2). 64 rows/block, 4 waves; wave w owns
// cols [w*64, w*64+64). Single 32KB LDS buffer (XOR swizzle ^((row&15)<<3)).
// STAGING IS BATCHED: all global loads of a phase issued back-to-back into
// registers (16KB in flight per wave), THEN converted+stored to LDS — attacks
// the measured 1.2 TB/s latency-bound HBM draw (Little's law: 4x outstanding).
// ---------------------------------------------------------------------------
__global__ __launch_bounds__(256) void k_phi(
    const float* __restrict__ X,
    const u16* __restrict__ W1s, const float* __restrict__ b1,
    const u16* __restrict__ W2s, const float* __restrict__ b2,
    u16* __restrict__ H, int N) {
  __shared__ __align__(16) u16 buf[64 * 256];
  const int tid = threadIdx.x, lane = tid & 63, wid = tid >> 6;
  const int g = lane >> 4, r16 = lane & 15;
  const int rbase = blockIdx.x * 64;
  const int swz = r16 << 3;  // u16-unit XOR for this thread's A-reads

  const u16* w1p = W1s + (size_t)(wid * 4) * 512 + lane * 8;  // + ks*8192 + n*512
  const u16* w2p = W2s + (size_t)(wid * 4) * 512 + lane * 8;

  // ---- stage phase 0: X cols [0,256): load-batch (16 in flight) then store ----
  {
    f32x4 xr[16];
#pragma unroll
    for (int it = 0; it < 16; ++it) {
      int u = it * 256 + tid;
      int row = u >> 6, c4 = u & 63;
      int crow = rbase + row; crow = crow < N ? crow : N - 1;
      xr[it] = *(const f32x4*)(X + (size_t)crow * 384 + c4 * 4);
    }
#pragma unroll
    for (int it = 0; it < 16; ++it) {
      int u = it * 256 + tid;
      int row = u >> 6, c4 = u & 63;
      uint2 pk;
      pk.x = (unsigned int)f2bf(xr[it][0]) | ((unsigned int)f2bf(xr[it][1]) << 16);
      pk.y = (unsigned int)f2bf(xr[it][2]) | ((unsigned int)f2bf(xr[it][3]) << 16);
      *(uint2*)(buf + row * 256 + ((c4 * 4) ^ ((row & 15) << 3))) = pk;
    }
  }
  __syncthreads();

  f32x4 acc[4][4];
#pragma unroll
  for (int m = 0; m < 4; ++m)
#pragma unroll
    for (int n = 0; n < 4; ++n) acc[m][n] = (f32x4){0.f, 0.f, 0.f, 0.f};

  // ---- layer 1, K phase 0 (ks 0..7), rolled ----
#pragma unroll 1
  for (int ks = 0; ks < 8; ++ks) {
    bf16x8 bfr[4];
#pragma unroll
    for (int n = 0; n < 4; ++n)
      bfr[n] = *(const bf16x8*)(w1p + (size_t)ks * 8192 + n * 512);
    const u16* bp = buf + ((ks * 32 + g * 8) ^ swz);
#pragma unroll
    for (int m = 0; m < 4; ++m) {
      bf16x8 af = *(const bf16x8*)(bp + (m * 16 + r16) * 256);
#pragma unroll
      for (int n = 0; n < 4; ++n)
        acc[m][n] = __builtin_amdgcn_mfma_f32_16x16x32_bf16(af, bfr[n], acc[m][n], 0, 0, 0);
    }
  }
  __syncthreads();  // done reading phase-0 A

  // ---- stage phase 1: X cols [256,384): load-batch (8 in flight) then store ----
  {
    f32x4 xr[8];
#pragma unroll
    for (int it = 0; it < 8; ++it) {
      int u = it * 256 + tid;
      int row = u >> 5, c4 = u & 31;
      int crow = rbase + row; crow = crow < N ? crow : N - 1;
      xr[it] = *(const f32x4*)(X + (size_t)crow * 384 + 256 + c4 * 4);
    }
#pragma unroll
    for (int it = 0; it < 8; ++it) {
      int u = it * 256 + tid;
      int row = u >> 5, c4 = u & 31;
      uint2 pk;
      pk.x = (unsigned int)f2bf(xr[it][0]) | ((unsigned int)f2bf(xr[it][1]) << 16);
      pk.y = (unsigned int)f2bf(xr[it][2]) | ((unsigned int)f2bf(xr[it][3]) << 16);
      *(uint2*)(buf + row * 256 + ((c4 * 4) ^ ((row & 15) << 3))) = pk;
    }
  }
  __syncthreads();

  // ---- layer 1, K phase 1 (ks 8..11), rolled ----
#pragma unroll 1
  for (int ksl = 0; ksl < 4; ++ksl) {
    bf16x8 bfr[4];
#pragma unroll
    for (int n = 0; n < 4; ++n)
      bfr[n] = *(const bf16x8*)(w1p + (size_t)(8 + ksl) * 8192 + n * 512);
    const u16* bp = buf + ((ksl * 32 + g * 8) ^ swz);
#pragma unroll
    for (int m = 0; m < 4; ++m) {
      bf16x8 af = *(const bf16x8*)(bp + (m * 16 + r16) * 256);
#pragma unroll
      for (int n = 0; n < 4; ++n)
        acc[m][n] = __builtin_amdgcn_mfma_f32_16x16x32_bf16(af, bfr[n], acc[m][n], 0, 0, 0);
    }
  }
  __syncthreads();  // done reading phase-1 A; buf free for h1

  // ---- h1 = relu(acc + b1) -> buf ----
  float bias1[4];
#pragma unroll
  for (int n = 0; n < 4; ++n) bias1[n] = b1[wid * 64 + n * 16 + r16];
#pragma unroll
  for (int m = 0; m < 4; ++m)
#pragma unroll
    for (int n = 0; n < 4; ++n)
#pragma unroll
      for (int rr = 0; rr < 4; ++rr) {
        int row = m * 16 + g * 4 + rr;
        int col = wid * 64 + n * 16 + r16;
        float v = fmaxf(acc[m][n][rr] + bias1[n], 0.f);
        buf[row * 256 + (col ^ ((row & 15) << 3))] = f2bf(v);
      }
  __syncthreads();

  // ---- layer 2 (reuse acc), rolled ----
#pragma unroll
  for (int m = 0; m < 4; ++m)
#pragma unroll
    for (int n = 0; n < 4; ++n) acc[m][n] = (f32x4){0.f, 0.f, 0.f, 0.f};
#pragma unroll 1
  for (int ks = 0; ks < 8; ++ks) {
    bf16x8 bfr[4];
#pragma unroll
    for (int n = 0; n < 4; ++n)
      bfr[n] = *(const bf16x8*)(w2p + (size_t)ks * 8192 + n * 512);
    const u16* bp = buf + ((ks * 32 + g * 8) ^ swz);
#pragma unroll
    for (int m = 0; m < 4; ++m) {
      bf16x8 af = *(const bf16x8*)(bp + (m * 16 + r16) * 256);
#pragma unroll
      for (int n = 0; n < 4; ++n)
        acc[m][n] = __builtin_amdgcn_mfma_f32_16x16x32_bf16(af, bfr[n], acc[m][n], 0, 0, 0);
    }
  }
  __syncthreads();  // done reading h1

  // ---- h2 = relu(acc + b2) -> buf ----
  float bias2[4];
#pragma unroll
  for (int n = 0; n < 4; ++n) bias2[n] = b2[wid * 64 + n * 16 + r16];
#pragma unroll
  for (int m = 0; m < 4; ++m)
#pragma unroll
    for (int n = 0; n < 4; ++n)
#pragma unroll
      for (int rr = 0; rr < 4; ++rr) {
        int row = m * 16 + g * 4 + rr;
        int col = wid * 64 + n * 16 + r16;
        float v = fmaxf(acc[m][n][rr] + bias2[n], 0.f);
        buf[row * 256 + (col ^ ((row & 15) << 3))] = f2bf(v);
      }
  __syncthreads();

  // ---- coalesced copy out ----
#pragma unroll 4
  for (int it = 0; it < 8; ++it) {
    int u = it * 256 + tid;
    int row = u >> 5, k8 = u & 31;
    uint4 d = *(const uint4*)(buf + row * 256 + ((k8 * 8) ^ ((row & 15) << 3)));
    int grow = rbase + row;
    if (grow < N) *(uint4*)(H + (size_t)grow * 256 + k8 * 8) = d;
  }
}

// ---------------------------------------------------------------------------
// k_cellsum: one wave per cell; pre-resolve sorted indices, __shfl-broadcast,
// 8-wide batched H-row loads (8 rows in flight per wave -> more MLP).
// ---------------------------------------------------------------------------
__global__ __launch_bounds__(256) void k_cellsum(
    const u16* __restrict__ H, const int* __restrict__ sorted,
    const int* __restrict__ offs, u16* __restrict__ CS, int M) {
  const int lane = threadIdx.x & 63, wid = threadIdx.x >> 6;
  int c = blockIdx.x * 4 + wid;
  if (c >= M) return;
  int s = offs[c], e = offs[c + 1];
  float a0 = 0.f, a1 = 0.f, a2 = 0.f, a3 = 0.f;
  for (int base = s; base < e; base += 64) {
    int cnt = e - base; if (cnt > 64) cnt = 64;
    int idx = sorted[base + (lane < cnt ? lane : 0)];
    int j = 0;
    for (; j + 8 <= cnt; j += 8) {
      ushort4 h[8];
#pragma unroll
      for (int q = 0; q < 8; ++q) {
        int nd = __shfl(idx, j + q);
        h[q] = *(const ushort4*)(H + (size_t)nd * 256 + lane * 4);
      }
#pragma unroll
      for (int q = 0; q < 8; ++q) {
        a0 += bf2f(h[q].x); a1 += bf2f(h[q].y);
        a2 += bf2f(h[q].z); a3 += bf2f(h[q].w);
      }
    }
    if (j + 4 <= cnt) {
      ushort4 h[4];
#pragma unroll
      for (int q = 0; q < 4; ++q) {
        int nd = __shfl(idx, j + q);
        h[q] = *(const ushort4*)(H + (size_t)nd * 256 + lane * 4);
      }
#pragma unroll
      for (int q = 0; q < 4; ++q) {
        a0 += bf2f(h[q].x); a1 += bf2f(h[q].y);
        a2 += bf2f(h[q].z); a3 += bf2f(h[q].w);
      }
      j += 4;
    }
    for (; j < cnt; ++j) {
      int nd = __shfl(idx, j);
      ushort4 h = *(const ushort4*)(H + (size_t)nd * 256 + lane * 4);
      a0 += bf2f(h.x); a1 += bf2f(h.y); a2 += bf2f(h.z); a3 += bf2f(h.w);
    }
  }
  ushort4 o;
  o.x = f2bf(a0); o.y = f2bf(a1); o.z = f2bf(a2); o.w = f2bf(a3);
  *(ushort4*)(CS + (size_t)c * 256 + lane * 4) = o;
}

// ---------------------------------------------------------------------------
// k_rho: OUT = relu(relu(CS@R1+c1)@R2+c2)@R3+c3. 64 rows/block, single 32KB
// LDS buffer, rolled ks-loops, batched CS staging (8 loads in flight).
// ---------------------------------------------------------------------------
__global__ __launch_bounds__(256) void k_rho(
    const u16* __restrict__ CS,
    const u16* __restrict__ R1s, const float* __restrict__ c1,
    const u16* __restrict__ R2s, const float* __restrict__ c2,
    const u16* __restrict__ R3s, const float* __restrict__ c3,
    float* __restrict__ OUT, int M) {
  __shared__ __align__(16) u16 buf[64 * 256];
  const int tid = threadIdx.x, lane = tid & 63, wid = tid >> 6;
  const int g = lane >> 4, r16 = lane & 15;
  const int rbase = blockIdx.x * 64;
  const int swz = r16 << 3;

  const u16* w1p = R1s + (size_t)(wid * 4) * 512 + lane * 8;
  const u16* w2p = R2s + (size_t)(wid * 4) * 512 + lane * 8;
  const u16* w3p = R3s + (size_t)(wid * 4) * 512 + lane * 8;

  // stage CS tile: load-batch then store
  {
    uint4 xr[8];
#pragma unroll
    for (int it = 0; it < 8; ++it) {
      int u = it * 256 + tid;
      int row = u >> 5, k8 = u & 31;
      int crow = rbase + row; crow = crow < M ? crow : M - 1;
      xr[it] = *(const uint4*)(CS + (size_t)crow * 256 + k8 * 8);
    }
#pragma unroll
    for (int it = 0; it < 8; ++it) {
      int u = it * 256 + tid;
      int row = u >> 5, k8 = u & 31;
      *(uint4*)(buf + row * 256 + ((k8 * 8) ^ ((row & 15) << 3))) = xr[it];
    }
  }
  __syncthreads();

  f32x4 acc[4][4];

  // ---- layer 1, rolled ----
#pragma unroll
  for (int m = 0; m < 4; ++m)
#pragma unroll
    for (int n = 0; n < 4; ++n) acc[m][n] = (f32x4){0.f, 0.f, 0.f, 0.f};
#pragma unroll 1
  for (int ks = 0; ks < 8; ++ks) {
    bf16x8 bfr[4];
#pragma unroll
    for (int n = 0; n < 4; ++n)
      bfr[n] = *(const bf16x8*)(w1p + (size_t)ks * 8192 + n * 512);
    const u16* bp = buf + ((ks * 32 + g * 8) ^ swz);
#pragma unroll
    for (int m = 0; m < 4; ++m) {
      bf16x8 af = *(const bf16x8*)(bp + (m * 16 + r16) * 256);
#pragma unroll
      for (int n = 0; n < 4; ++n)
        acc[m][n] = __builtin_amdgcn_mfma_f32_16x16x32_bf16(af, bfr[n], acc[m][n], 0, 0, 0);
    }
  }
  __syncthreads();  // done reading CS tile

  float bias1[4];
#pragma unroll
  for (int n = 0; n < 4; ++n) bias1[n] = c1[wid * 64 + n * 16 + r16];
#pragma unroll
  for (int m = 0; m < 4; ++m)
#pragma unroll
    for (int n = 0; n < 4; ++n)
#pragma unroll
      for (int rr = 0; rr < 4; ++rr) {
        int row = m * 16 + g * 4 + rr;
        int col = wid * 64 + n * 16 + r16;
        float v = fmaxf(acc[m][n][rr] + bias1[n], 0.f);
        buf[row * 256 + (col ^ ((row & 15) << 3))] = f2bf(v);
      }
  __syncthreads();

  // ---- layer 2, rolled ----
#pragma unroll
  for (int m = 0; m < 4; ++m)
#pragma unroll
    for (int n = 0; n < 4; ++n) acc[m][n] = (f32x4){0.f, 0.f, 0.f, 0.f};
#pragma unroll 1
  for (int ks = 0; ks < 8; ++ks) {
    bf16x8 bfr[4];
#pragma unroll
    for (int n = 0; n < 4; ++n)
      bfr[n] = *(const bf16x8*)(w2p + (size_t)ks * 8192 + n * 512);
    const u16* bp = buf + ((ks * 32 + g * 8) ^ swz);
#pragma unroll
    for (int m = 0; m < 4; ++m) {
      bf16x8 af = *(const bf16x8*)(bp + (m * 16 + r16) * 256);
#pragma unroll
      for (int n = 0; n < 4; ++n)
        acc[m][n] = __builtin_amdgcn_mfma_f32_16x16x32_bf16(af, bfr[n], acc[m][n], 0, 0, 0);
    }
  }
  __syncthreads();  // done reading h1

  float bias2[4];
#pragma unroll
  for (int n = 0; n < 4; ++n) bias2[n] = c2[wid * 64 + n * 16 + r16];
#pragma unroll
  for (int m = 0; m < 4; ++m)
#pragma unroll
    for (int n = 0; n < 4; ++n)
#pragma unroll
      for (int rr = 0; rr < 4; ++rr) {
        int row = m * 16 + g * 4 + rr;
        int col = wid * 64 + n * 16 + r16;
        float v = fmaxf(acc[m][n][rr] + bias2[n], 0.f);
        buf[row * 256 + (col ^ ((row & 15) << 3))] = f2bf(v);
      }
  __syncthreads();

  // ---- layer 3 (no relu), rolled, direct fp32 stores ----
#pragma unroll
  for (int m = 0; m < 4; ++m)
#pragma unroll
    for (int n = 0; n < 4; ++n) acc[m][n] = (f32x4){0.f, 0.f, 0.f, 0.f};
#pragma unroll 1
  for (int ks = 0; ks < 8; ++ks) {
    bf16x8 bfr[4];
#pragma unroll
    for (int n = 0; n < 4; ++n)
      bfr[n] = *(const bf16x8*)(w3p + (size_t)ks * 8192 + n * 512);
    const u16* bp = buf + ((ks * 32 + g * 8) ^ swz);
#pragma unroll
    for (int m = 0; m < 4; ++m) {
      bf16x8 af = *(const bf16x8*)(bp + (m * 16 + r16) * 256);
#pragma unroll
      for (int n = 0; n < 4; ++n)
        acc[m][n] = __builtin_amdgcn_mfma_f32_16x16x32_bf16(af, bfr[n], acc[m][n], 0, 0, 0);
    }
  }
#pragma unroll
  for (int n = 0; n < 4; ++n) {
    float bias = c3[wid * 64 + n * 16 + r16];
#pragma unroll
    for (int m = 0; m < 4; ++m)
#pragma unroll
      for (int rr = 0; rr < 4; ++rr) {
        int grow = rbase + m * 16 + g * 4 + rr;
        if (grow < M) OUT[(size_t)grow * 256 + wid * 64 + n * 16 + r16] = acc[m][n][rr] + bias;
      }
  }
}

// ---------------------------------------------------------------------------
extern "C" void kernel_launch(void* const* d_in, const int* in_sizes, int n_in,
                              void* d_out, int out_size, void* d_ws, size_t ws_size,
                              hipStream_t stream) {
  const float* X    = (const float*)d_in[0];
  const int* nodes  = (const int*)d_in[1];
  const int* cells  = (const int*)d_in[2];
  const float* W1   = (const float*)d_in[4];
  const float* b1   = (const float*)d_in[5];
  const float* W2   = (const float*)d_in[6];
  const float* b2   = (const float*)d_in[7];
  const float* R1   = (const float*)d_in[8];
  const float* c1   = (const float*)d_in[9];
  const float* R2   = (const float*)d_in[10];
  const float* c2   = (const float*)d_in[11];
  const float* R3   = (const float*)d_in[12];
  const float* c3   = (const float*)d_in[13];
  float* OUT = (float*)d_out;

  const int N = in_sizes[0] / 384;   // 100000
  const int E = in_sizes[1];         // 400000
  const int M = out_size / 256;      // 50000

  char* ws = (char*)d_ws;
  size_t off = 0;
  auto alloc = [&](size_t b) { size_t o = off; off += (b + 255) & ~(size_t)255; return o; };
  u16* W1s    = (u16*)(ws + alloc((size_t)12 * 16 * 64 * 8 * 2));
  u16* W2s    = (u16*)(ws + alloc((size_t)8 * 16 * 64 * 8 * 2));
  u16* R1s    = (u16*)(ws + alloc((size_t)8 * 16 * 64 * 8 * 2));
  u16* R2s    = (u16*)(ws + alloc((size_t)8 * 16 * 64 * 8 * 2));
  u16* R3s    = (u16*)(ws + alloc((size_t)8 * 16 * 64 * 8 * 2));
  u16* H      = (u16*)(ws + alloc((size_t)N * 256 * 2));
  u16* CS     = (u16*)(ws + alloc((size_t)M * 256 * 2));
  int* counts = (int*)(ws + alloc((size_t)M * 4));
  int* offs   = (int*)(ws + alloc((size_t)(M + 1) * 4));
  int* cursor = (int*)(ws + alloc((size_t)M * 4));
  int* sorted = (int*)(ws + alloc((size_t)E * 4));
  int* bsum   = (int*)(ws + alloc((size_t)256 * 4));

  const int NB = (M + 255) / 256;

  hipMemsetAsync(counts, 0, (size_t)M * 4, stream);
  k_prep<<<176, 256, 0, stream>>>(W1, W2, R1, R2, R3, W1s, W2s, R1s, R2s, R3s);
  k_hist<<<(E + 255) / 256, 256, 0, stream>>>(cells, counts, E);
  k_scan1<<<NB, 256, 0, stream>>>(counts, offs, bsum, M);
  k_scan2<<<1, 256, 0, stream>>>(bsum, NB);
  k_scan3<<<(M + 256) / 256, 256, 0, stream>>>(offs, bsum, cursor, M, E);
  k_scatter<<<(E + 255) / 256, 256, 0, stream>>>(cells, nodes, cursor, sorted, E);
  k_phi<<<(N + 63) / 64, 256, 0, stream>>>(X, W1s, b1, W2s, b2, H, N);
  k_cellsum<<<(M + 3) / 4, 256, 0, stream>>>(H, sorted, offs, CS, M);
  k_rho<<<(M + 63) / 64, 256, 0, stream>>>(CS, R1s, c1, R2s, c2, R3s, c3, OUT, M);
}

// Round 8
// 219.019 us; speedup vs baseline: 1.1837x; 1.0136x over previous
//
#include <hip/hip_runtime.h>

typedef unsigned short u16;
typedef __bf16 bf16x8 __attribute__((ext_vector_type(8)));
typedef float f32x4 __attribute__((ext_vector_type(4)));

__device__ __forceinline__ u16 f2bf(float f) {
  unsigned int u = __builtin_bit_cast(unsigned int, f);
  u += 0x7fffu + ((u >> 16) & 1u);
  return (u16)(u >> 16);
}
__device__ __forceinline__ float bf2f(u16 h) {
  unsigned int u = ((unsigned int)h) << 16;
  return __builtin_bit_cast(float, u);
}

// ---------------------------------------------------------------------------
// k_prep: fp32 weights -> bf16 MFMA B-fragment order.
// Fragment (ks, nt, lane): 8 elems W[ks*32 + (lane>>4)*8 + j][nt*16 + (lane&15)]
// at dst[((ks*16+nt)*64 + lane)*8 + j].
// ---------------------------------------------------------------------------
__global__ __launch_bounds__(256) void k_prep(
    const float* __restrict__ W1, const float* __restrict__ W2,
    const float* __restrict__ R1, const float* __restrict__ R2, const float* __restrict__ R3,
    u16* __restrict__ W1s, u16* __restrict__ W2s,
    u16* __restrict__ R1s, u16* __restrict__ R2s, u16* __restrict__ R3s) {
  int t = blockIdx.x * 256 + threadIdx.x;
  const float* src; u16* dst; int lt;
  if (t < 12288) { src = W1; dst = W1s; lt = t; }
  else {
    int u = t - 12288;
    int m = u >> 13;
    lt = u & 8191;
    if (m == 0)      { src = W2; dst = W2s; }
    else if (m == 1) { src = R1; dst = R1s; }
    else if (m == 2) { src = R2; dst = R2s; }
    else if (m == 3) { src = R3; dst = R3s; }
    else return;
  }
  int lane = lt & 63;
  int nt = (lt >> 6) & 15;
  int ks = lt >> 10;
  int col = nt * 16 + (lane & 15);
  int kb = ks * 32 + (lane >> 4) * 8;
  union { u16 u[8]; uint4 v; } o;
#pragma unroll
  for (int j = 0; j < 8; ++j) o.u[j] = f2bf(src[(size_t)(kb + j) * 256 + col]);
  *(uint4*)(dst + (size_t)lt * 8) = o.v;
}

// ---------------------------------------------------------------------------
// CSR build: histogram -> 3-stage multi-block exclusive scan -> scatter.
// ---------------------------------------------------------------------------
__global__ __launch_bounds__(256) void k_hist(const int* __restrict__ cells,
                                              int* __restrict__ counts, int E) {
  int e = blockIdx.x * 256 + threadIdx.x;
  if (e < E) atomicAdd(&counts[cells[e]], 1);
}

__global__ __launch_bounds__(256) void k_scan1(const int* __restrict__ counts,
                                               int* __restrict__ offs,
                                               int* __restrict__ bsum, int M) {
  __shared__ int ws[4];
  int tid = threadIdx.x, lane = tid & 63, wid = tid >> 6;
  int i = blockIdx.x * 256 + tid;
  int v = (i < M) ? counts[i] : 0;
  int x = v;
#pragma unroll
  for (int s = 1; s < 64; s <<= 1) { int y = __shfl_up(x, s); if (lane >= s) x += y; }
  if (lane == 63) ws[wid] = x;
  __syncthreads();
  int pre = 0;
#pragma unroll
  for (int w = 0; w < 4; ++w) if (w < wid) pre += ws[w];
  if (i < M) offs[i] = pre + x - v;
  if (tid == 255) bsum[blockIdx.x] = pre + x;
}

__global__ __launch_bounds__(256) void k_scan2(int* __restrict__ bsum, int nb) {
  __shared__ int ws[4];
  int tid = threadIdx.x, lane = tid & 63, wid = tid >> 6;
  int v = (tid < nb) ? bsum[tid] : 0;
  int x = v;
#pragma unroll
  for (int s = 1; s < 64; s <<= 1) { int y = __shfl_up(x, s); if (lane >= s) x += y; }
  if (lane == 63) ws[wid] = x;
  __syncthreads();
  int pre = 0;
#pragma unroll
  for (int w = 0; w < 4; ++w) if (w < wid) pre += ws[w];
  if (tid < nb) bsum[tid] = pre + x - v;
}

__global__ __launch_bounds__(256) void k_scan3(int* __restrict__ offs,
                                               const int* __restrict__ bsum,
                                               int* __restrict__ cursor, int M, int E) {
  int i = blockIdx.x * 256 + threadIdx.x;
  if (i < M) { int o = offs[i] + bsum[blockIdx.x]; offs[i] = o; cursor[i] = o; }
  if (i == M) offs[M] = E;
}

__global__ __launch_bounds__(256) void k_scatter(const int* __restrict__ cells,
                                                 const int* __restrict__ nodes,
                                                 int* __restrict__ cursor,
                                                 int* __restrict__ sorted, int E) {
  int e = blockIdx.x * 256 + threadIdx.x;
  if (e < E) {
    int c = cells[e];
    int p = atomicAdd(&cursor[c], 1);
    sorted[p] = nodes[e];
  }
}

// ---------------------------------------------------------------------------
// k_phi: H = relu(relu(X@W1+b1)@W2+b2). TILE-PIPELINED: grid-stride over
// 32-row tiles; loads for tile t+1 are issued before compute of tile t and
// written to LDS after it (issue-early / write-late) — global loads stay in
// flight ~continuously instead of only inside barrier-gated staging windows.
// LDS: xbuf 24KB (32x384 bf16, XOR swizzle) + hbuf 16KB -> 4 blocks/CU.
// Wave w owns cols [w*64, w*64+64); acc[2][4] per wave (32 rows).
// ---------------------------------------------------------------------------
__global__ __launch_bounds__(256) void k_phi(
    const float* __restrict__ X,
    const u16* __restrict__ W1s, const float* __restrict__ b1,
    const u16* __restrict__ W2s, const float* __restrict__ b2,
    u16* __restrict__ H, int N) {
  __shared__ __align__(16) u16 xbuf[32 * 384];
  __shared__ __align__(16) u16 hbuf[32 * 256];
  const int tid = threadIdx.x, lane = tid & 63, wid = tid >> 6;
  const int g = lane >> 4, r16 = lane & 15;
  const int swz = r16 << 3;
  const int T = (N + 31) >> 5;
  const int step = gridDim.x;

  const u16* w1p = W1s + (size_t)(wid * 4) * 512 + lane * 8;  // + ks*8192 + n*512
  const u16* w2p = W2s + (size_t)(wid * 4) * 512 + lane * 8;

  float bias1[4], bias2[4];
#pragma unroll
  for (int n = 0; n < 4; ++n) {
    bias1[n] = b1[wid * 64 + n * 16 + r16];
    bias2[n] = b2[wid * 64 + n * 16 + r16];
  }

  f32x4 xr[12];

  auto issue = [&](int t) {
#pragma unroll
    for (int it = 0; it < 12; ++it) {
      int u = it * 256 + tid;
      int row = u / 96, c4 = u - row * 96;
      int crow = t * 32 + row; crow = crow < N ? crow : N - 1;
      xr[it] = *(const f32x4*)(X + (size_t)crow * 384 + c4 * 4);
    }
  };
  auto stagewrite = [&]() {
#pragma unroll
    for (int it = 0; it < 12; ++it) {
      int u = it * 256 + tid;
      int row = u / 96, c4 = u - row * 96;
      uint2 pk;
      pk.x = (unsigned int)f2bf(xr[it][0]) | ((unsigned int)f2bf(xr[it][1]) << 16);
      pk.y = (unsigned int)f2bf(xr[it][2]) | ((unsigned int)f2bf(xr[it][3]) << 16);
      *(uint2*)(xbuf + row * 384 + ((c4 * 4) ^ ((row & 15) << 3))) = pk;
    }
  };

  const int t0 = blockIdx.x;
  if (t0 >= T) return;

  // prologue: stage tile t0, put tile t0+step in flight
  issue(t0);
  stagewrite();
  __syncthreads();
  issue(t0 + step);

  for (int t = t0; t < T; t += step) {
    // ---- layer 1: 12 ks from xbuf ----
    f32x4 acc[2][4];
#pragma unroll
    for (int m = 0; m < 2; ++m)
#pragma unroll
      for (int n = 0; n < 4; ++n) acc[m][n] = (f32x4){0.f, 0.f, 0.f, 0.f};
#pragma unroll 4
    for (int ks = 0; ks < 12; ++ks) {
      bf16x8 bfr[4];
#pragma unroll
      for (int n = 0; n < 4; ++n)
        bfr[n] = *(const bf16x8*)(w1p + (size_t)ks * 8192 + n * 512);
      const u16* bp = xbuf + ((ks * 32 + g * 8) ^ swz);
#pragma unroll
      for (int m = 0; m < 2; ++m) {
        bf16x8 af = *(const bf16x8*)(bp + (m * 16 + r16) * 384);
#pragma unroll
        for (int n = 0; n < 4; ++n)
          acc[m][n] = __builtin_amdgcn_mfma_f32_16x16x32_bf16(af, bfr[n], acc[m][n], 0, 0, 0);
      }
    }
    __syncthreads();  // all waves done reading xbuf(tile t)

    // ---- write-late: stage tile t+step into xbuf (waits vmcnt internally) ----
    stagewrite();

    // ---- h1 -> hbuf ----
#pragma unroll
    for (int m = 0; m < 2; ++m)
#pragma unroll
      for (int n = 0; n < 4; ++n)
#pragma unroll
        for (int rr = 0; rr < 4; ++rr) {
          int row = m * 16 + g * 4 + rr;
          int col = wid * 64 + n * 16 + r16;
          float v = fmaxf(acc[m][n][rr] + bias1[n], 0.f);
          hbuf[row * 256 + (col ^ ((row & 15) << 3))] = f2bf(v);
        }
    __syncthreads();

    // ---- issue-early: loads for tile t+2*step (clamped; harmless past end) ----
    issue(t + 2 * step);

    // ---- layer 2: 8 ks from hbuf ----
#pragma unroll
    for (int m = 0; m < 2; ++m)
#pragma unroll
      for (int n = 0; n < 4; ++n) acc[m][n] = (f32x4){0.f, 0.f, 0.f, 0.f};
#pragma unroll 4
    for (int ks = 0; ks < 8; ++ks) {
      bf16x8 bfr[4];
#pragma unroll
      for (int n = 0; n < 4; ++n)
        bfr[n] = *(const bf16x8*)(w2p + (size_t)ks * 8192 + n * 512);
      const u16* bp = hbuf + ((ks * 32 + g * 8) ^ swz);
#pragma unroll
      for (int m = 0; m < 2; ++m) {
        bf16x8 af = *(const bf16x8*)(bp + (m * 16 + r16) * 256);
#pragma unroll
        for (int n = 0; n < 4; ++n)
          acc[m][n] = __builtin_amdgcn_mfma_f32_16x16x32_bf16(af, bfr[n], acc[m][n], 0, 0, 0);
      }
    }
    __syncthreads();  // done reading h1

    // ---- h2 -> hbuf ----
#pragma unroll
    for (int m = 0; m < 2; ++m)
#pragma unroll
      for (int n = 0; n < 4; ++n)
#pragma unroll
        for (int rr = 0; rr < 4; ++rr) {
          int row = m * 16 + g * 4 + rr;
          int col = wid * 64 + n * 16 + r16;
          float v = fmaxf(acc[m][n][rr] + bias2[n], 0.f);
          hbuf[row * 256 + (col ^ ((row & 15) << 3))] = f2bf(v);
        }
    __syncthreads();

    // ---- coalesced copy out ----
#pragma unroll
    for (int it = 0; it < 4; ++it) {
      int u = it * 256 + tid;
      int row = u >> 5, k8 = u & 31;
      uint4 d = *(const uint4*)(hbuf + row * 256 + ((k8 * 8) ^ ((row & 15) << 3)));
      int grow = t * 32 + row;
      if (grow < N) *(uint4*)(H + (size_t)grow * 256 + k8 * 8) = d;
    }
  }
}

// ---------------------------------------------------------------------------
// k_cellsum: one wave per cell; pre-resolve sorted indices, __shfl-broadcast,
// 8-wide batched H-row loads (8 rows in flight per wave).
// ---------------------------------------------------------------------------
__global__ __launch_bounds__(256) void k_cellsum(
    const u16* __restrict__ H, const int* __restrict__ sorted,
    const int* __restrict__ offs, u16* __restrict__ CS, int M) {
  const int lane = threadIdx.x & 63, wid = threadIdx.x >> 6;
  int c = blockIdx.x * 4 + wid;
  if (c >= M) return;
  int s = offs[c], e = offs[c + 1];
  float a0 = 0.f, a1 = 0.f, a2 = 0.f, a3 = 0.f;
  for (int base = s; base < e; base += 64) {
    int cnt = e - base; if (cnt > 64) cnt = 64;
    int idx = sorted[base + (lane < cnt ? lane : 0)];
    int j = 0;
    for (; j + 8 <= cnt; j += 8) {
      ushort4 h[8];
#pragma unroll
      for (int q = 0; q < 8; ++q) {
        int nd = __shfl(idx, j + q);
        h[q] = *(const ushort4*)(H + (size_t)nd * 256 + lane * 4);
      }
#pragma unroll
      for (int q = 0; q < 8; ++q) {
        a0 += bf2f(h[q].x); a1 += bf2f(h[q].y);
        a2 += bf2f(h[q].z); a3 += bf2f(h[q].w);
      }
    }
    if (j + 4 <= cnt) {
      ushort4 h[4];
#pragma unroll
      for (int q = 0; q < 4; ++q) {
        int nd = __shfl(idx, j + q);
        h[q] = *(const ushort4*)(H + (size_t)nd * 256 + lane * 4);
      }
#pragma unroll
      for (int q = 0; q < 4; ++q) {
        a0 += bf2f(h[q].x); a1 += bf2f(h[q].y);
        a2 += bf2f(h[q].z); a3 += bf2f(h[q].w);
      }
      j += 4;
    }
    for (; j < cnt; ++j) {
      int nd = __shfl(idx, j);
      ushort4 h = *(const ushort4*)(H + (size_t)nd * 256 + lane * 4);
      a0 += bf2f(h.x); a1 += bf2f(h.y); a2 += bf2f(h.z); a3 += bf2f(h.w);
    }
  }
  ushort4 o;
  o.x = f2bf(a0); o.y = f2bf(a1); o.z = f2bf(a2); o.w = f2bf(a3);
  *(ushort4*)(CS + (size_t)c * 256 + lane * 4) = o;
}

// ---------------------------------------------------------------------------
// k_rho: OUT = relu(relu(CS@R1+c1)@R2+c2)@R3+c3. Same tile-pipelined
// structure (32-row tiles, issue-early/write-late), 3 layers.
// LDS: xbuf 16KB + hbuf 16KB.
// ---------------------------------------------------------------------------
__global__ __launch_bounds__(256) void k_rho(
    const u16* __restrict__ CS,
    const u16* __restrict__ R1s, const float* __restrict__ c1,
    const u16* __restrict__ R2s, const float* __restrict__ c2,
    const u16* __restrict__ R3s, const float* __restrict__ c3,
    float* __restrict__ OUT, int M) {
  __shared__ __align__(16) u16 xbuf[32 * 256];
  __shared__ __align__(16) u16 hbuf[32 * 256];
  const int tid = threadIdx.x, lane = tid & 63, wid = tid >> 6;
  const int g = lane >> 4, r16 = lane & 15;
  const int swz = r16 << 3;
  const int T = (M + 31) >> 5;
  const int step = gridDim.x;

  const u16* w1p = R1s + (size_t)(wid * 4) * 512 + lane * 8;
  const u16* w2p = R2s + (size_t)(wid * 4) * 512 + lane * 8;
  const u16* w3p = R3s + (size_t)(wid * 4) * 512 + lane * 8;

  float bias1[4], bias2[4], bias3[4];
#pragma unroll
  for (int n = 0; n < 4; ++n) {
    bias1[n] = c1[wid * 64 + n * 16 + r16];
    bias2[n] = c2[wid * 64 + n * 16 + r16];
    bias3[n] = c3[wid * 64 + n * 16 + r16];
  }

  uint4 xr[4];
  auto issue = [&](int t) {
#pragma unroll
    for (int it = 0; it < 4; ++it) {
      int u = it * 256 + tid;
      int row = u >> 5, k8 = u & 31;
      int crow = t * 32 + row; crow = crow < M ? crow : M - 1;
      xr[it] = *(const uint4*)(CS + (size_t)crow * 256 + k8 * 8);
    }
  };
  auto stagewrite = [&]() {
#pragma unroll
    for (int it = 0; it < 4; ++it) {
      int u = it * 256 + tid;
      int row = u >> 5, k8 = u & 31;
      *(uint4*)(xbuf + row * 256 + ((k8 * 8) ^ ((row & 15) << 3))) = xr[it];
    }
  };

  const int t0 = blockIdx.x;
  if (t0 >= T) return;
  issue(t0);
  stagewrite();
  __syncthreads();
  issue(t0 + step);

  for (int t = t0; t < T; t += step) {
    f32x4 acc[2][4];

    // ---- layer 1: 8 ks from xbuf ----
#pragma unroll
    for (int m = 0; m < 2; ++m)
#pragma unroll
      for (int n = 0; n < 4; ++n) acc[m][n] = (f32x4){0.f, 0.f, 0.f, 0.f};
#pragma unroll 4
    for (int ks = 0; ks < 8; ++ks) {
      bf16x8 bfr[4];
#pragma unroll
      for (int n = 0; n < 4; ++n)
        bfr[n] = *(const bf16x8*)(w1p + (size_t)ks * 8192 + n * 512);
      const u16* bp = xbuf + ((ks * 32 + g * 8) ^ swz);
#pragma unroll
      for (int m = 0; m < 2; ++m) {
        bf16x8 af = *(const bf16x8*)(bp + (m * 16 + r16) * 256);
#pragma unroll
        for (int n = 0; n < 4; ++n)
          acc[m][n] = __builtin_amdgcn_mfma_f32_16x16x32_bf16(af, bfr[n], acc[m][n], 0, 0, 0);
      }
    }
    __syncthreads();  // done reading xbuf(tile t)

    stagewrite();     // tile t+step -> xbuf

    // ---- h1 -> hbuf ----
#pragma unroll
    for (int m = 0; m < 2; ++m)
#pragma unroll
      for (int n = 0; n < 4; ++n)
#pragma unroll
        for (int rr = 0; rr < 4; ++rr) {
          int row = m * 16 + g * 4 + rr;
          int col = wid * 64 + n * 16 + r16;
          float v = fmaxf(acc[m][n][rr] + bias1[n], 0.f);
          hbuf[row * 256 + (col ^ ((row & 15) << 3))] = f2bf(v);
        }
    __syncthreads();

    issue(t + 2 * step);

    // ---- layer 2: 8 ks from hbuf ----
#pragma unroll
    for (int m = 0; m < 2; ++m)
#pragma unroll
      for (int n = 0; n < 4; ++n) acc[m][n] = (f32x4){0.f, 0.f, 0.f, 0.f};
#pragma unroll 4
    for (int ks = 0; ks < 8; ++ks) {
      bf16x8 bfr[4];
#pragma unroll
      for (int n = 0; n < 4; ++n)
        bfr[n] = *(const bf16x8*)(w2p + (size_t)ks * 8192 + n * 512);
      const u16* bp = hbuf + ((ks * 32 + g * 8) ^ swz);
#pragma unroll
      for (int m = 0; m < 2; ++m) {
        bf16x8 af = *(const bf16x8*)(bp + (m * 16 + r16) * 256);
#pragma unroll
        for (int n = 0; n < 4; ++n)
          acc[m][n] = __builtin_amdgcn_mfma_f32_16x16x32_bf16(af, bfr[n], acc[m][n], 0, 0, 0);
      }
    }
    __syncthreads();  // done reading h1

    // ---- h2 -> hbuf ----
#pragma unroll
    for (int m = 0; m < 2; ++m)
#pragma unroll
      for (int n = 0; n < 4; ++n)
#pragma unroll
        for (int rr = 0; rr < 4; ++rr) {
          int row = m * 16 + g * 4 + rr;
          int col = wid * 64 + n * 16 + r16;
          float v = fmaxf(acc[m][n][rr] + bias2[n], 0.f);
          hbuf[row * 256 + (col ^ ((row & 15) << 3))] = f2bf(v);
        }
    __syncthreads();

    // ---- layer 3: 8 ks from hbuf, direct fp32 stores ----
#pragma unroll
    for (int m = 0; m < 2; ++m)
#pragma unroll
      for (int n = 0; n < 4; ++n) acc[m][n] = (f32x4){0.f, 0.f, 0.f, 0.f};
#pragma unroll 4
    for (int ks = 0; ks < 8; ++ks) {
      bf16x8 bfr[4];
#pragma unroll
      for (int n = 0; n < 4; ++n)
        bfr[n] = *(const bf16x8*)(w3p + (size_t)ks * 8192 + n * 512);
      const u16* bp = hbuf + ((ks * 32 + g * 8) ^ swz);
#pragma unroll
      for (int m = 0; m < 2; ++m) {
        bf16x8 af = *(const bf16x8*)(bp + (m * 16 + r16) * 256);
#pragma unroll
        for (int n = 0; n < 4; ++n)
          acc[m][n] = __builtin_amdgcn_mfma_f32_16x16x32_bf16(af, bfr[n], acc[m][n], 0, 0, 0);
      }
    }
#pragma unroll
    for (int n = 0; n < 4; ++n) {
#pragma unroll
      for (int m = 0; m < 2; ++m)
#pragma unroll
        for (int rr = 0; rr < 4; ++rr) {
          int grow = t * 32 + m * 16 + g * 4 + rr;
          if (grow < M)
            OUT[(size_t)grow * 256 + wid * 64 + n * 16 + r16] = acc[m][n][rr] + bias3[n];
        }
    }
  }
}

// ---------------------------------------------------------------------------
extern "C" void kernel_launch(void* const* d_in, const int* in_sizes, int n_in,
                              void* d_out, int out_size, void* d_ws, size_t ws_size,
                              hipStream_t stream) {
  const float* X    = (const float*)d_in[0];
  const int* nodes  = (const int*)d_in[1];
  const int* cells  = (const int*)d_in[2];
  const float* W1   = (const float*)d_in[4];
  const float* b1   = (const float*)d_in[5];
  const float* W2   = (const float*)d_in[6];
  const float* b2   = (const float*)d_in[7];
  const float* R1   = (const float*)d_in[8];
  const float* c1   = (const float*)d_in[9];
  const float* R2   = (const float*)d_in[10];
  const float* c2   = (const float*)d_in[11];
  const float* R3   = (const float*)d_in[12];
  const float* c3   = (const float*)d_in[13];
  float* OUT = (float*)d_out;

  const int N = in_sizes[0] / 384;   // 100000
  const int E = in_sizes[1];         // 400000
  const int M = out_size / 256;      // 50000

  char* ws = (char*)d_ws;
  size_t off = 0;
  auto alloc = [&](size_t b) { size_t o = off; off += (b + 255) & ~(size_t)255; return o; };
  u16* W1s    = (u16*)(ws + alloc((size_t)12 * 16 * 64 * 8 * 2));
  u16* W2s    = (u16*)(ws + alloc((size_t)8 * 16 * 64 * 8 * 2));
  u16* R1s    = (u16*)(ws + alloc((size_t)8 * 16 * 64 * 8 * 2));
  u16* R2s    = (u16*)(ws + alloc((size_t)8 * 16 * 64 * 8 * 2));
  u16* R3s    = (u16*)(ws + alloc((size_t)8 * 16 * 64 * 8 * 2));
  u16* H      = (u16*)(ws + alloc((size_t)N * 256 * 2));
  u16* CS     = (u16*)(ws + alloc((size_t)M * 256 * 2));
  int* counts = (int*)(ws + alloc((size_t)M * 4));
  int* offs   = (int*)(ws + alloc((size_t)(M + 1) * 4));
  int* cursor = (int*)(ws + alloc((size_t)M * 4));
  int* sorted = (int*)(ws + alloc((size_t)E * 4));
  int* bsum   = (int*)(ws + alloc((size_t)256 * 4));

  const int NB = (M + 255) / 256;

  hipMemsetAsync(counts, 0, (size_t)M * 4, stream);
  k_prep<<<176, 256, 0, stream>>>(W1, W2, R1, R2, R3, W1s, W2s, R1s, R2s, R3s);
  k_hist<<<(E + 255) / 256, 256, 0, stream>>>(cells, counts, E);
  k_scan1<<<NB, 256, 0, stream>>>(counts, offs, bsum, M);
  k_scan2<<<1, 256, 0, stream>>>(bsum, NB);
  k_scan3<<<(M + 256) / 256, 256, 0, stream>>>(offs, bsum, cursor, M, E);
  k_scatter<<<(E + 255) / 256, 256, 0, stream>>>(cells, nodes, cursor, sorted, E);
  k_phi<<<1024, 256, 0, stream>>>(X, W1s, b1, W2s, b2, H, N);
  k_cellsum<<<(M + 3) / 4, 256, 0, stream>>>(H, sorted, offs, CS, M);
  k_rho<<<512, 256, 0, stream>>>(CS, R1s, c1, R2s, c2, R3s, c3, OUT, M);
}